// Round 7
// baseline (335.015 us; speedup 1.0000x reference)
//
#include <hip/hip_runtime.h>

#define S 2048
#define D 2048
#define H 16
#define HD 128
#define N3 6144  // 3*D

typedef __attribute__((ext_vector_type(8))) _Float16 f16x8;
typedef __attribute__((ext_vector_type(4))) float f32x4;
typedef unsigned short ushort_t;
typedef unsigned int uint_t;

// ---------------------------------------------------------------------------
// f16 helpers (v_cvt_f16_f32 is RNE)
// ---------------------------------------------------------------------------
__device__ __forceinline__ ushort_t f16_rne(float f) {
    _Float16 h = (_Float16)f;
    return __builtin_bit_cast(ushort_t, h);
}
__device__ __forceinline__ float f16_f32(ushort_t u) {
    return (float)__builtin_bit_cast(_Float16, u);
}

// f32 row-major -> f16 (activations). R19: 32B/thread (G13 vectorize).
__global__ __launch_bounds__(256) void convert_f16_kernel(
    const float* __restrict__ in, ushort_t* __restrict__ hi)
{
    const int base = blockIdx.x * 512 + threadIdx.x;   // per float4, x2
    const float4* in4 = (const float4*)in;
    float4 a = in4[base];
    float4 b = in4[base + 256];
    ((ushort4*)hi)[base] = make_ushort4(f16_rne(a.x), f16_rne(a.y),
                                        f16_rne(a.z), f16_rne(a.w));
    ((ushort4*)hi)[base + 256] = make_ushort4(f16_rne(b.x), f16_rne(b.y),
                                              f16_rne(b.z), f16_rne(b.w));
}

// W [K][N] f32 -> Wt [N][K] f16 (transpose + convert), 32x32 tiles.
// R19: load phase vectorized to ONE float4/thread (was 4 scalar 4B loads —
// Common-mistake #2). LDS stores scalar (stride-33 keeps both phases
// conflict-free: bank = (row + 4c + i) % 32). Read phase unchanged (proven).
__global__ __launch_bounds__(256) void convert_t_kernel(
    const float* __restrict__ in, ushort_t* __restrict__ hi,
    int Kdim, int Ndim)
{
    __shared__ float tile[32][33];
    const int k0 = blockIdx.x * 32, n0 = blockIdx.y * 32;
    const int row = threadIdx.x >> 3;        // 0..31
    const int c4  = (threadIdx.x & 7) * 4;   // 0..28
    float4 v = *(const float4*)&in[(size_t)(k0 + row) * Ndim + n0 + c4];
    tile[row][c4 + 0] = v.x;
    tile[row][c4 + 1] = v.y;
    tile[row][c4 + 2] = v.z;
    tile[row][c4 + 3] = v.w;
    __syncthreads();
    const int n  = threadIdx.x >> 3;        // 0..31 local col
    const int kc = (threadIdx.x & 7) * 4;   // 0..28 local k chunk
    const float v0 = tile[kc + 0][n], v1 = tile[kc + 1][n];
    const float v2 = tile[kc + 2][n], v3 = tile[kc + 3][n];
    const size_t off = (size_t)(n0 + n) * Kdim + k0 + kc;
    *(ushort4*)&hi[off] = make_ushort4(f16_rne(v0), f16_rne(v1),
                                       f16_rne(v2), f16_rne(v3));
}

// ---------------------------------------------------------------------------
// async global->LDS, 16 B per lane, wave-uniform LDS base (HW adds lane*16).
// ---------------------------------------------------------------------------
__device__ __forceinline__ void gload16(const ushort_t* g, ushort_t* l) {
    __builtin_amdgcn_global_load_lds(
        (const __attribute__((address_space(1))) unsigned int*)g,
        (__attribute__((address_space(3))) unsigned int*)l, 16, 0, 0);
}

__device__ __forceinline__ void vwait4() { asm volatile("s_waitcnt vmcnt(4)" ::: "memory"); }
__device__ __forceinline__ void vwait3() { asm volatile("s_waitcnt vmcnt(3)" ::: "memory"); }
__device__ __forceinline__ void vwait0() { asm volatile("s_waitcnt vmcnt(0)" ::: "memory"); }
__device__ __forceinline__ void lwait0() { asm volatile("s_waitcnt lgkmcnt(0)" ::: "memory"); }

// ---------------------------------------------------------------------------
// R17 GEMM core (PROVEN R5/R6: qkv 85us, MfmaUtil 25.5%, 0 conflicts):
// 128x128 tile, 8 waves (512 thr), BK=64, dbuf 64 KB -> 2 blocks/CU =
// 16 waves/CU. TLP is the binding constraint (R5 A/B). Both-sides XOR
// swizzle; 2 barriers/tile; counted vmcnt(4). NO XCD swizzle (R4: L2 thrash).
// ---------------------------------------------------------------------------
#define QNT 32   // D / 64 K-tiles

__device__ __forceinline__ void mm_core_v4(
    const ushort_t* __restrict__ At, const ushort_t* __restrict__ Bt,
    ushort_t* lds, const int t, f32x4 (&acc)[4][2])
{
    const int w = t >> 6, lane = t & 63;
    const int lr = lane & 15, quad = lane >> 4;
    const int wm = (w >> 2) * 64;     // 2 m-groups
    const int wn = (w & 3) * 32;      // 4 n-groups

    const int srow = w * 8 + (lane >> 3);
    const int schk = ((lane & 7) ^ (lane >> 3)) * 8;
    const int ldsw = w * 512;   // wave-uniform

    auto stageAB = [&](int Tt) {
        ushort_t* dbase = lds + (Tt & 1) * 16384;
        const size_t koff = (size_t)Tt * 64 + schk;
        gload16(At + (size_t)srow * D + koff,        dbase + ldsw);
        gload16(At + (size_t)(srow + 64) * D + koff, dbase + 4096 + ldsw);
        gload16(Bt + (size_t)srow * D + koff,        dbase + 8192 + ldsw);
        gload16(Bt + (size_t)(srow + 64) * D + koff, dbase + 12288 + ldsw);
    };

    const int aoff = (wm + lr) * 64;
    const int boff = 8192 + (wn + lr) * 64;
    const int sw0 = ((0 * 4 + quad) ^ (lr & 7)) * 8;
    const int sw1 = ((1 * 4 + quad) ^ (lr & 7)) * 8;

    stageAB(0);
    stageAB(1);
    vwait4();                       // tile 0 landed (tile 1 in flight)
    __builtin_amdgcn_sched_barrier(0);
    __builtin_amdgcn_s_barrier();

    f16x8 a[4], b[2];
    for (int T = 0; T < QNT; T++) {
        const ushort_t* base = lds + (T & 1) * 16384;
        // ---- kk = 0 slice
        #pragma unroll
        for (int i = 0; i < 4; i++)
            a[i] = *(const f16x8*)&base[aoff + i * 1024 + sw0];
        #pragma unroll
        for (int n = 0; n < 2; n++)
            b[n] = *(const f16x8*)&base[boff + n * 1024 + sw0];
        lwait0();
        __builtin_amdgcn_sched_barrier(0);
        __builtin_amdgcn_s_setprio(1);
        #pragma unroll
        for (int i = 0; i < 4; i++)
            #pragma unroll
            for (int n = 0; n < 2; n++)
                acc[i][n] = __builtin_amdgcn_mfma_f32_16x16x32_f16(
                    a[i], b[n], acc[i][n], 0, 0, 0);
        __builtin_amdgcn_s_setprio(0);
        // ---- kk = 1 slice
        #pragma unroll
        for (int i = 0; i < 4; i++)
            a[i] = *(const f16x8*)&base[aoff + i * 1024 + sw1];
        #pragma unroll
        for (int n = 0; n < 2; n++)
            b[n] = *(const f16x8*)&base[boff + n * 1024 + sw1];
        lwait0();
        __builtin_amdgcn_sched_barrier(0);
        __builtin_amdgcn_s_barrier();   // all waves done reading buf T&1
        if (T < QNT - 2) stageAB(T + 2);
        __builtin_amdgcn_s_setprio(1);
        #pragma unroll
        for (int i = 0; i < 4; i++)
            #pragma unroll
            for (int n = 0; n < 2; n++)
                acc[i][n] = __builtin_amdgcn_mfma_f32_16x16x32_f16(
                    a[i], b[n], acc[i][n], 0, 0, 0);
        __builtin_amdgcn_s_setprio(0);
        if (T < QNT - 2)       vwait4();   // T+1 landed; T+2 in flight
        else if (T == QNT - 2) vwait0();   // drain last tile
        __builtin_amdgcn_s_barrier();
    }
}

// ---------------------------------------------------------------------------
// R18 dense core: 64x128 tile, 8 waves, BK=64, dbuf 48 KB, same schedule.
// ---------------------------------------------------------------------------
__device__ __forceinline__ void mm_core_v4h(
    const ushort_t* __restrict__ At, const ushort_t* __restrict__ Bt,
    ushort_t* lds, const int t, f32x4 (&acc)[2][2])
{
    const int w = t >> 6, lane = t & 63;
    const int lr = lane & 15, quad = lane >> 4;
    const int wm = (w >> 2) * 32;     // 2 m-groups over 64 rows
    const int wn = (w & 3) * 32;      // 4 n-groups over 128 cols

    const int srow = w * 8 + (lane >> 3);          // 0..63
    const int schk = ((lane & 7) ^ (lane >> 3)) * 8;
    const int ldsw = w * 512;

    auto stageAB = [&](int Tt) {
        ushort_t* dbase = lds + (Tt & 1) * 12288;
        const size_t koff = (size_t)Tt * 64 + schk;
        gload16(At + (size_t)srow * D + koff,        dbase + ldsw);          // A 0..63
        gload16(Bt + (size_t)srow * D + koff,        dbase + 4096 + ldsw);   // B 0..63
        gload16(Bt + (size_t)(srow + 64) * D + koff, dbase + 8192 + ldsw);   // B 64..127
    };

    const int aoff = (wm + lr) * 64;
    const int boff = 4096 + (wn + lr) * 64;
    const int sw0 = ((0 * 4 + quad) ^ (lr & 7)) * 8;
    const int sw1 = ((1 * 4 + quad) ^ (lr & 7)) * 8;

    stageAB(0);
    stageAB(1);
    vwait3();
    __builtin_amdgcn_sched_barrier(0);
    __builtin_amdgcn_s_barrier();

    f16x8 a[2], b[2];
    for (int T = 0; T < QNT; T++) {
        const ushort_t* base = lds + (T & 1) * 12288;
        // ---- kk = 0 slice
        #pragma unroll
        for (int i = 0; i < 2; i++)
            a[i] = *(const f16x8*)&base[aoff + i * 1024 + sw0];
        #pragma unroll
        for (int n = 0; n < 2; n++)
            b[n] = *(const f16x8*)&base[boff + n * 1024 + sw0];
        lwait0();
        __builtin_amdgcn_sched_barrier(0);
        __builtin_amdgcn_s_setprio(1);
        #pragma unroll
        for (int i = 0; i < 2; i++)
            #pragma unroll
            for (int n = 0; n < 2; n++)
                acc[i][n] = __builtin_amdgcn_mfma_f32_16x16x32_f16(
                    a[i], b[n], acc[i][n], 0, 0, 0);
        __builtin_amdgcn_s_setprio(0);
        // ---- kk = 1 slice
        #pragma unroll
        for (int i = 0; i < 2; i++)
            a[i] = *(const f16x8*)&base[aoff + i * 1024 + sw1];
        #pragma unroll
        for (int n = 0; n < 2; n++)
            b[n] = *(const f16x8*)&base[boff + n * 1024 + sw1];
        lwait0();
        __builtin_amdgcn_sched_barrier(0);
        __builtin_amdgcn_s_barrier();
        if (T < QNT - 2) stageAB(T + 2);
        __builtin_amdgcn_s_setprio(1);
        #pragma unroll
        for (int i = 0; i < 2; i++)
            #pragma unroll
            for (int n = 0; n < 2; n++)
                acc[i][n] = __builtin_amdgcn_mfma_f32_16x16x32_f16(
                    a[i], b[n], acc[i][n], 0, 0, 0);
        __builtin_amdgcn_s_setprio(0);
        if (T < QNT - 2)       vwait3();
        else if (T == QNT - 2) vwait0();
        __builtin_amdgcn_s_barrier();
    }
}

// ---------------------------------------------------------------------------
// QKV GEMM (f16 1-term, v4 core, 512 thr). q/k/v all stored f16.
// ---------------------------------------------------------------------------
__global__ __launch_bounds__(512, 4) void gemm_qkv_mfma(
    const ushort_t* __restrict__ xh,
    const ushort_t* __restrict__ Wth,
    const float* __restrict__ bias, const float* __restrict__ freqs,
    const int* __restrict__ input_pos,
    ushort_t* __restrict__ qhg, ushort_t* __restrict__ khg,
    ushort_t* __restrict__ vhg)
{
    __shared__ ushort_t lds[32768];   // 64 KB
    const int t = threadIdx.x;
    const int col0 = blockIdx.x * 128;
    const int row0 = blockIdx.y * 128;

    f32x4 acc[4][2] = {};
    mm_core_v4(xh + (size_t)row0 * D, Wth + (size_t)col0 * D, lds, t, acc);

    const int lane = t & 63;
    const int quad = lane >> 4;
    const int lr   = lane & 15;
    const int w = t >> 6;
    const int wm = (w >> 2) * 64;
    const int wn = (w & 3) * 32;

    const int which = col0 >> 11;           // 0=q 1=k 2=v (128 | 2048)
    const int hh = (col0 & 2047) >> 7;

    if (which == 2) {
        ushort_t* vh_b = vhg + (size_t)hh * HD * S;
        #pragma unroll
        for (int nt = 0; nt < 2; nt++) {
            const int d = wn + nt * 16 + lr;
            const float bsc = bias[col0 + d];
            #pragma unroll
            for (int mt = 0; mt < 4; mt++) {
                #pragma unroll
                for (int reg = 0; reg < 4; reg++) {
                    const int m = row0 + wm + mt * 16 + quad * 4 + reg;
                    const float v = acc[mt][nt][reg] + bsc;
                    vh_b[(size_t)d * S + input_pos[m]] = f16_rne(v);
                }
            }
        }
    } else {
        ushort_t* oh_b = ((which == 0) ? qhg : khg) + (size_t)hh * S * HD;
        #pragma unroll
        for (int nt = 0; nt < 2; nt++) {
            const int d = wn + nt * 16 + lr;
            const float bsc = bias[col0 + d];
            #pragma unroll
            for (int mt = 0; mt < 4; mt++) {
                #pragma unroll
                for (int reg = 0; reg < 4; reg++) {
                    const int m = row0 + wm + mt * 16 + quad * 4 + reg;
                    const float v = acc[mt][nt][reg] + bsc;
                    const float* fc = &freqs[((size_t)m * 64 + (d >> 1)) * 2];
                    const float cc = fc[0], ss = fc[1];
                    const float p = __shfl_xor(v, 1);
                    const float o = (d & 1) ? (v * cc + p * ss) : (v * cc - p * ss);
                    const ushort_t hv = f16_rne(o);
                    const int hp = __shfl_xor((int)hv, 1);
                    if (!(d & 1)) {
                        const int srowg = (which == 0) ? m : input_pos[m];
                        *(uint_t*)&oh_b[(size_t)srowg * HD + d] =
                            (uint_t)hv | ((uint_t)hp << 16);
                    }
                }
            }
        }
    }
}

// ---------------------------------------------------------------------------
// Dense GEMM (f16 1-term, v4h core, 512 thr, 64x128 tiles): out = ctx@Wd + b
// ---------------------------------------------------------------------------
__global__ __launch_bounds__(512, 4) void gemm_dense_mfma(
    const ushort_t* __restrict__ Ah,
    const ushort_t* __restrict__ Wth,
    const float* __restrict__ bias, float* __restrict__ out)
{
    __shared__ ushort_t lds[24576];   // 48 KB
    const int t = threadIdx.x;
    const int col0 = blockIdx.x * 128;
    const int row0 = blockIdx.y * 64;

    f32x4 acc[2][2] = {};
    mm_core_v4h(Ah + (size_t)row0 * D, Wth + (size_t)col0 * D, lds, t, acc);

    const int lane = t & 63;
    const int quad = lane >> 4;
    const int lr   = lane & 15;
    const int w = t >> 6;
    const int wm = (w >> 2) * 32;
    const int wn = (w & 3) * 32;

    #pragma unroll
    for (int nt = 0; nt < 2; nt++) {
        const int n = col0 + wn + nt * 16 + lr;
        const float bsc = bias[n];
        #pragma unroll
        for (int mt = 0; mt < 2; mt++) {
            #pragma unroll
            for (int reg = 0; reg < 4; reg++) {
                const int m = row0 + wm + mt * 16 + quad * 4 + reg;
                const float o = acc[mt][nt][reg] + bsc;
                const float po = __shfl_xor(o, 1);
                if (!(n & 1))
                    *(float2*)&out[(size_t)m * D + n] = make_float2(o, po);
            }
        }
    }
}

// ---------------------------------------------------------------------------
// MFMA flash attention, SPLIT-K x2 (KVBLK=32). R19: DEFER-MAX (T13) — the
// per-tile 4-step shfl reduce (4 dependent ~30cy LDS-lat ops) + 3 exp2 +
// 36-mul O-rescale was ~260 VALU-cyc/tile vs 82 cyc MFMA: softmax chain was
// the critical path. Now: wave-vote __all(max(z) <= m + 8); pass (common
// after tile 0) -> P = exp2(z - m) directly, no reduce/rescale/m-update
// (P <= 2^8 = 256, f16-safe; l <= 2.6e5, f32-safe; combine normalizes
// exactly). Fail -> original full path. First tile always fails (m=-1e30),
// seeding m with the exact tile max. + setprio around MFMA clusters (m191).
// ---------------------------------------------------------------------------
__global__ __launch_bounds__(256, 4) void attn_mfma_kernel(
    const ushort_t* __restrict__ qhg, const ushort_t* __restrict__ khg,
    const ushort_t* __restrict__ vhg,
    float* __restrict__ Opart, float* __restrict__ MLpart)
{
    __shared__ ushort_t Khs[2][4096];   // [buf][hf*512.. key*32 + d8] per wave chunk
    __shared__ ushort_t Vhs[2][4096];   // [buf][dim*32 + key8]
    __shared__ ushort_t Ps[64 * 32];

    const int bi   = blockIdx.x;           // 0..1023
    const int h    = (bi & 7) + 8 * ((bi >> 3) & 1);
    const int half = (bi >> 4) & 1;
    const int qi   = bi >> 5;              // 0..31
    const int r = (h & 8) ? qi : (31 - qi);
    const int q0 = r * 64;
    const int nhalf = r + 1;
    const int kt0 = half * nhalf;
    const int kt1 = kt0 + nhalf;
    const int t = threadIdx.x;
    const int w = t >> 6, lane = t & 63;
    const int lr = lane & 15, quad = lane >> 4;

    const size_t qrow = (size_t)h * S + q0 + w * 16 + lr;
    f16x8 qf[4];
    #pragma unroll
    for (int ks = 0; ks < 4; ks++)
        qf[ks] = *(const f16x8*)&qhg[qrow * HD + ks * 32 + quad * 8];

    const ushort_t* kh_b = khg + (size_t)h * S * HD;
    const ushort_t* vh_b = vhg + (size_t)h * HD * S;

    const int keyq = lane >> 2;   // 0..15
    const int sub  = lane & 3;    // 16B chunk index

    auto stage = [&](int kt, int buf) {
        const int k0 = kt * 32;
        #pragma unroll
        for (int hf = 0; hf < 2; hf++) {
            const size_t ksrc = (size_t)(k0 + hf * 16 + keyq) * HD + w * 32 + sub * 8;
            gload16(kh_b + ksrc, &Khs[buf][w * 1024 + hf * 512]);
            const int dim = w * 32 + hf * 16 + keyq;
            const size_t vsrc = (size_t)dim * S + k0 + sub * 8;
            gload16(vh_b + vsrc, &Vhs[buf][(w * 32 + hf * 16) * 32]);
        }
    };

    f32x4 O[8] = {};
    f32x4 Ol = {0.f, 0.f, 0.f, 0.f};   // ones-column: per-row denom (unnorm)
    float mrow[4];
    #pragma unroll
    for (int rr = 0; rr < 4; rr++) mrow[rr] = -1e30f;

    f16x8 onesv;
    #pragma unroll
    for (int i = 0; i < 8; i++) onesv[i] = (_Float16)1.0f;

    const float kSc = 0.08838834764831845f * 1.4426950408889634f; // scale*log2e

    stage(kt0, 0);

    for (int kt = kt0; kt < kt1; kt++) {
        const int k0 = kt * 32;
        const int cur = (kt - kt0) & 1;
        __syncthreads();  // drains vmcnt -> tile kt visible; buf cur^1 free

        if (kt + 1 < kt1) stage(kt + 1, cur ^ 1);

        // ---- scores (f16 q*k, f32 accum)
        f32x4 sa[2];
        __builtin_amdgcn_s_setprio(1);
        #pragma unroll
        for (int nt = 0; nt < 2; nt++) {
            f32x4 s = {0.f, 0.f, 0.f, 0.f};
            #pragma unroll
            for (int ks = 0; ks < 4; ks++) {
                f16x8 kf = *(const f16x8*)&Khs[cur][ks * 1024 + (nt * 16 + lr) * 32 + quad * 8];
                s = __builtin_amdgcn_mfma_f32_16x16x32_f16(qf[ks], kf, s, 0, 0, 0);
            }
            sa[nt] = s;
        }
        __builtin_amdgcn_s_setprio(0);

        const int rowbase = q0 + w * 16 + quad * 4;
        const bool need_mask = (k0 + 31) > (q0 + w * 16);
        float z[4][2];
        #pragma unroll
        for (int rr = 0; rr < 4; rr++) {
            z[rr][0] = sa[0][rr] * kSc;
            z[rr][1] = sa[1][rr] * kSc;
            if (need_mask) {
                const int rowg = rowbase + rr;
                if (k0 + lr > rowg)      z[rr][0] = -1e30f;
                if (k0 + 16 + lr > rowg) z[rr][1] = -1e30f;
            }
        }

        bool okl = true;
        #pragma unroll
        for (int rr = 0; rr < 4; rr++)
            okl = okl && (fmaxf(z[rr][0], z[rr][1]) <= mrow[rr] + 8.0f);

        float pv0[4], pv1[4];
        if (__all(okl)) {
            // common path: max didn't grow past threshold — no reduce,
            // no rescale, no m update. P bounded by 2^8.
            #pragma unroll
            for (int rr = 0; rr < 4; rr++) {
                pv0[rr] = exp2f(z[rr][0] - mrow[rr]);
                pv1[rr] = exp2f(z[rr][1] - mrow[rr]);
            }
        } else {
            float alpha[4];
            #pragma unroll
            for (int rr = 0; rr < 4; rr++) {
                float rm = fmaxf(z[rr][0], z[rr][1]);
                #pragma unroll
                for (int off = 1; off < 16; off <<= 1)
                    rm = fmaxf(rm, __shfl_xor(rm, off));
                const float nm = fmaxf(mrow[rr], rm);
                alpha[rr] = exp2f(mrow[rr] - nm);
                pv0[rr] = exp2f(z[rr][0] - nm);
                pv1[rr] = exp2f(z[rr][1] - nm);
                mrow[rr] = nm;
            }
            #pragma unroll
            for (int nt = 0; nt < 8; nt++)
                #pragma unroll
                for (int rr = 0; rr < 4; rr++)
                    O[nt][rr] *= alpha[rr];
            #pragma unroll
            for (int rr = 0; rr < 4; rr++)
                Ol[rr] *= alpha[rr];
        }

        #pragma unroll
        for (int rr = 0; rr < 4; rr++) {
            const int prow = (w * 16 + quad * 4 + rr) * 32;
            Ps[prow + lr]      = f16_rne(pv0[rr]);
            Ps[prow + 16 + lr] = f16_rne(pv1[rr]);
        }
        // no barrier: each wave reads only its own P rows (lgkmcnt orders)

        const f16x8 pf = *(const f16x8*)&Ps[(w * 16 + lr) * 32 + quad * 8];
        __builtin_amdgcn_s_setprio(1);
        #pragma unroll
        for (int nt = 0; nt < 8; nt++) {
            f16x8 vf = *(const f16x8*)&Vhs[cur][(nt * 16 + lr) * 32 + quad * 8];
            O[nt] = __builtin_amdgcn_mfma_f32_16x16x32_f16(pf, vf, O[nt], 0, 0, 0);
        }
        Ol = __builtin_amdgcn_mfma_f32_16x16x32_f16(pf, onesv, Ol, 0, 0, 0);
        __builtin_amdgcn_s_setprio(0);
    }

    // ---- store unnormalized partial O + (m, l) for the combine pass
    float* Ob = Opart + (size_t)bi * 64 * 128;
    #pragma unroll
    for (int rr = 0; rr < 4; rr++) {
        const int row = w * 16 + quad * 4 + rr;
        #pragma unroll
        for (int nt = 0; nt < 8; nt++)
            Ob[(size_t)row * 128 + nt * 16 + lr] = O[nt][rr];
        if (lr == 0) {
            MLpart[(size_t)bi * 128 + row * 2 + 0] = mrow[rr];
            MLpart[(size_t)bi * 128 + row * 2 + 1] = Ol[rr];
        }
    }
}

// ---------------------------------------------------------------------------
// Exact online-softmax merge of the two split-K halves -> ctxh (f16).
// ---------------------------------------------------------------------------
__global__ __launch_bounds__(128) void attn_combine_kernel(
    const float* __restrict__ Opart, const float* __restrict__ MLpart,
    ushort_t* __restrict__ ctxh)
{
    const int qt = blockIdx.x;   // 0..31 (qi in attn kernel)
    const int h  = blockIdx.y;   // 0..15
    const int t  = threadIdx.x;  // 0..127
    const int b0 = h | (qt << 5);          // half 0
    const int b1 = b0 | (1 << 4);          // half 1
    const int r = (h & 8) ? qt : (31 - qt);
    const int q0 = r * 64;

    __shared__ float sc[64][2];
    if (t < 64) {
        const float m0 = MLpart[(size_t)b0 * 128 + t * 2 + 0];
        const float l0 = MLpart[(size_t)b0 * 128 + t * 2 + 1];
        const float m1 = MLpart[(size_t)b1 * 128 + t * 2 + 0];
        const float l1 = MLpart[(size_t)b1 * 128 + t * 2 + 1];
        const float m = fmaxf(m0, m1);
        const float a0 = exp2f(m0 - m), a1 = exp2f(m1 - m);
        const float inv = 1.0f / (l0 * a0 + l1 * a1);
        sc[t][0] = a0 * inv;
        sc[t][1] = a1 * inv;
    }
    __syncthreads();

    const float* O0 = Opart + (size_t)b0 * 64 * 128;
    const float* O1 = Opart + (size_t)b1 * 64 * 128;
    for (int row = 0; row < 64; row++) {
        const float o = O0[(size_t)row * 128 + t] * sc[row][0] +
                        O1[(size_t)row * 128 + t] * sc[row][1];
        ctxh[(size_t)(q0 + row) * D + h * HD + t] = f16_rne(o);
    }
}

// ---------------------------------------------------------------------------
// Fallback f32 path (R2, known-good) for small workspace.
// ---------------------------------------------------------------------------
__global__ __launch_bounds__(256) void gemm_qkv_kernel(
    const float* __restrict__ x, const float* __restrict__ W,
    const float* __restrict__ bias, const float* __restrict__ freqs,
    const int* __restrict__ input_pos,
    float* __restrict__ qb, float* __restrict__ kb, float* __restrict__ vb)
{
    __shared__ float As[16][68];
    __shared__ float Bs[16][64];
    const int bx = blockIdx.x;
    const int by = blockIdx.y;
    const int tid = threadIdx.x;
    const int tx = tid & 15, ty = tid >> 4;
    const int row0 = by * 64, col0 = bx * 64;
    const int am = tid >> 2;
    const int ak = (tid & 3) * 4;
    const int bk = tid >> 4;
    const int bn = (tid & 15) * 4;
    float acc[4][4] = {};
    for (int k0 = 0; k0 < D; k0 += 16) {
        float4 av = *(const float4*)&x[(size_t)(row0 + am) * D + k0 + ak];
        float4 bv = *(const float4*)&W[(size_t)(k0 + bk) * N3 + col0 + bn];
        __syncthreads();
        As[ak + 0][am] = av.x; As[ak + 1][am] = av.y;
        As[ak + 2][am] = av.z; As[ak + 3][am] = av.w;
        *(float4*)&Bs[bk][bn] = bv;
        __syncthreads();
        #pragma unroll
        for (int k = 0; k < 16; k++) {
            float4 a4 = *(const float4*)&As[k][ty * 4];
            float4 b4 = *(const float4*)&Bs[k][tx * 4];
            float a[4] = {a4.x, a4.y, a4.z, a4.w};
            float b[4] = {b4.x, b4.y, b4.z, b4.w};
            #pragma unroll
            for (int r = 0; r < 4; r++)
                #pragma unroll
                for (int c = 0; c < 4; c++)
                    acc[r][c] += a[r] * b[c];
        }
    }
    const int j0 = col0 + tx * 4;
    const int which = j0 >> 11;
    const int hh = (j0 & 2047) >> 7;
    const int d0 = j0 & 127;
    const float bv0 = bias[j0 + 0], bv1 = bias[j0 + 1];
    const float bv2 = bias[j0 + 2], bv3 = bias[j0 + 3];
    #pragma unroll
    for (int r = 0; r < 4; r++) {
        const int grow = row0 + ty * 4 + r;
        float v0 = acc[r][0] + bv0, v1 = acc[r][1] + bv1;
        float v2 = acc[r][2] + bv2, v3 = acc[r][3] + bv3;
        if (which == 2) {
            const int pos = input_pos[grow];
            float4 o4 = make_float4(v0, v1, v2, v3);
            *(float4*)&vb[((size_t)hh * S + pos) * HD + d0] = o4;
        } else {
            const float* fc = &freqs[((size_t)grow * 64 + (d0 >> 1)) * 2];
            float c0 = fc[0], s0 = fc[1], c1 = fc[2], s1 = fc[3];
            float o0 = v0 * c0 - v1 * s0, o1 = v1 * c0 + v0 * s0;
            float o2 = v2 * c1 - v3 * s1, o3 = v3 * c1 + v2 * s1;
            float4 o4 = make_float4(o0, o1, o2, o3);
            if (which == 0) {
                *(float4*)&qb[((size_t)hh * S + grow) * HD + d0] = o4;
            } else {
                const int pos = input_pos[grow];
                *(float4*)&kb[((size_t)hh * S + pos) * HD + d0] = o4;
            }
        }
    }
}

#define BQ 64
#define ABK 32
#define QSTR 132
#define KVSTR 132
#define PSTR 68

__global__ __launch_bounds__(256) void attn_kernel(
    const float* __restrict__ qb, const float* __restrict__ kb,
    const float* __restrict__ vb, float* __restrict__ ctx)
{
    __shared__ float Qs[BQ * QSTR];
    __shared__ float KV[ABK * KVSTR];
    __shared__ float Psf[ABK * PSTR];

    const int pa = blockIdx.x;
    const int h  = blockIdx.y;
    const int t  = threadIdx.x;
    const int ty = t >> 4, tx = t & 15;
    const int i0  = ty * 4;
    const int j0  = tx * 2;
    const int dd0 = tx * 8;
    const int lr = t >> 3;
    const int lc = (t & 7) * 4;

    const float* kbase = kb + (size_t)h * S * HD;
    const float* vbase = vb + (size_t)h * S * HD;
    const float kSc = 0.08838834764831845f * 1.4426950408889634f;

    for (int ph = 0; ph < 2; ph++) {
        const int r = (ph == 0) ? pa : 31 - pa;
        const int q0 = r * BQ;
        const int ntiles = 2 * r + 2;

        #pragma unroll
        for (int pp = 0; pp < 2; pp++) {
            const int iq = lr + pp * 32;
            const float* src = qb + ((size_t)h * S + q0 + iq) * HD;
            #pragma unroll
            for (int ch = 0; ch < 4; ch++)
                *(float4*)&Qs[iq * QSTR + lc + ch * 32] =
                    *(const float4*)&src[lc + ch * 32];
        }

        float O[4][8] = {};
        float m[4], l[4];
        #pragma unroll
        for (int rr = 0; rr < 4; rr++) { m[rr] = -1e30f; l[rr] = 0.f; }

        float4 kpref[4];
        #pragma unroll
        for (int ch = 0; ch < 4; ch++)
            kpref[ch] = *(const float4*)&kbase[(size_t)lr * HD + lc + ch * 32];

        __syncthreads();

        for (int kt = 0; kt < ntiles; kt++) {
            const int k0 = kt * ABK;

            #pragma unroll
            for (int ch = 0; ch < 4; ch++)
                *(float4*)&KV[lr * KVSTR + lc + ch * 32] = kpref[ch];
            __syncthreads();

            float4 vpref[4];
            #pragma unroll
            for (int ch = 0; ch < 4; ch++)
                vpref[ch] = *(const float4*)&vbase[(size_t)(k0 + lr) * HD + lc + ch * 32];

            float acc[4][2] = {};
            #pragma unroll 4
            for (int d0 = 0; d0 < HD; d0 += 4) {
                float4 ka = *(const float4*)&KV[(j0 + 0) * KVSTR + d0];
                float4 kb4 = *(const float4*)&KV[(j0 + 1) * KVSTR + d0];
                #pragma unroll
                for (int rr = 0; rr < 4; rr++) {
                    float4 q4 = *(const float4*)&Qs[(i0 + rr) * QSTR + d0];
                    acc[rr][0] += q4.x * ka.x + q4.y * ka.y + q4.z * ka.z + q4.w * ka.w;
                    acc[rr][1] += q4.x * kb4.x + q4.y * kb4.y + q4.z * kb4.z + q4.w * kb4.w;
                }
            }

            const bool need_mask = (k0 + ABK - 1) > q0;
            float p[4][2], alpha[4];
            #pragma unroll
            for (int rr = 0; rr < 4; rr++) {
                float z0 = acc[rr][0] * kSc;
                float z1 = acc[rr][1] * kSc;
                if (need_mask) {
                    if (k0 + j0 + 0 > q0 + i0 + rr) z0 = -1e30f;
                    if (k0 + j0 + 1 > q0 + i0 + rr) z1 = -1e30f;
                }
                float rmax = fmaxf(z0, z1);
                #pragma unroll
                for (int off = 1; off < 16; off <<= 1)
                    rmax = fmaxf(rmax, __shfl_xor(rmax, off, 16));
                const float nm = fmaxf(m[rr], rmax);
                alpha[rr] = exp2f(m[rr] - nm);
                p[rr][0] = exp2f(z0 - nm);
                p[rr][1] = exp2f(z1 - nm);
                float ts = p[rr][0] + p[rr][1];
                #pragma unroll
                for (int off = 1; off < 16; off <<= 1)
                    ts += __shfl_xor(ts, off, 16);
                l[rr] = l[rr] * alpha[rr] + ts;
                m[rr] = nm;
            }
            __syncthreads();

            #pragma unroll
            for (int ch = 0; ch < 4; ch++)
                *(float4*)&KV[lr * KVSTR + lc + ch * 32] = vpref[ch];
            *(float4*)&Psf[(j0 + 0) * PSTR + i0] =
                make_float4(p[0][0], p[1][0], p[2][0], p[3][0]);
            *(float4*)&Psf[(j0 + 1) * PSTR + i0] =
                make_float4(p[0][1], p[1][1], p[2][1], p[3][1]);
            if (kt + 1 < ntiles) {
                #pragma unroll
                for (int ch = 0; ch < 4; ch++)
                    kpref[ch] = *(const float4*)&kbase[(size_t)(k0 + ABK + lr) * HD + lc + ch * 32];
            }
            __syncthreads();

            #pragma unroll
            for (int rr = 0; rr < 4; rr++)
                #pragma unroll
                for (int c = 0; c < 8; c++)
                    O[rr][c] *= alpha[rr];
            #pragma unroll 4
            for (int j = 0; j < ABK; j++) {
                float4 pj = *(const float4*)&Psf[j * PSTR + i0];
                float4 v0 = *(const float4*)&KV[j * KVSTR + dd0];
                float4 v1 = *(const float4*)&KV[j * KVSTR + dd0 + 4];
                const float pr[4] = {pj.x, pj.y, pj.z, pj.w};
                const float vv[8] = {v0.x, v0.y, v0.z, v0.w, v1.x, v1.y, v1.z, v1.w};
                #pragma unroll
                for (int rr = 0; rr < 4; rr++)
                    #pragma unroll
                    for (int c = 0; c < 8; c++)
                        O[rr][c] += pr[rr] * vv[c];
            }
            __syncthreads();
        }

        #pragma unroll
        for (int rr = 0; rr < 4; rr++) {
            const float inv = 1.0f / l[rr];
            const int qg = q0 + i0 + rr;
            float4 o0 = make_float4(O[rr][0] * inv, O[rr][1] * inv,
                                    O[rr][2] * inv, O[rr][3] * inv);
            float4 o1 = make_float4(O[rr][4] * inv, O[rr][5] * inv,
                                    O[rr][6] * inv, O[rr][7] * inv);
            float* dst = &ctx[((size_t)qg * H + h) * HD + dd0];
            *(float4*)&dst[0] = o0;
            *(float4*)&dst[4] = o1;
        }
        __syncthreads();
    }
}

__global__ __launch_bounds__(256) void gemm_dense_kernel(
    const float* __restrict__ A, const float* __restrict__ W,
    const float* __restrict__ bias, float* __restrict__ out)
{
    __shared__ float As[16][68];
    __shared__ float Bs[16][64];
    const int bx = blockIdx.x;
    const int by = blockIdx.y;
    const int tid = threadIdx.x;
    const int tx = tid & 15, ty = tid >> 4;
    const int row0 = by * 64, col0 = bx * 64;
    const int am = tid >> 2;
    const int ak = (tid & 3) * 4;
    const int bk = tid >> 4;
    const int bn = (tid & 15) * 4;
    float acc[4][4] = {};
    for (int k0 = 0; k0 < D; k0 += 16) {
        float4 av = *(const float4*)&A[(size_t)(row0 + am) * D + k0 + ak];
        float4 bv = *(const float4*)&W[(size_t)(k0 + bk) * D + col0 + bn];
        __syncthreads();
        As[ak + 0][am] = av.x; As[ak + 1][am] = av.y;
        As[ak + 2][am] = av.z; As[ak + 3][am] = av.w;
        *(float4*)&Bs[bk][bn] = bv;
        __syncthreads();
        #pragma unroll
        for (int k = 0; k < 16; k++) {
            float4 a4 = *(const float4*)&As[k][ty * 4];
            float4 b4 = *(const float4*)&Bs[k][tx * 4];
            float a[4] = {a4.x, a4.y, a4.z, a4.w};
            float b[4] = {b4.x, b4.y, b4.z, b4.w};
            #pragma unroll
            for (int r = 0; r < 4; r++)
                #pragma unroll
                for (int c = 0; c < 4; c++)
                    acc[r][c] += a[r] * b[c];
        }
    }
    const int j0 = col0 + tx * 4;
    const float bv0 = bias[j0 + 0], bv1 = bias[j0 + 1];
    const float bv2 = bias[j0 + 2], bv3 = bias[j0 + 3];
    #pragma unroll
    for (int r = 0; r < 4; r++) {
        const int grow = row0 + ty * 4 + r;
        float4 o4 = make_float4(acc[r][0] + bv0, acc[r][1] + bv1,
                                acc[r][2] + bv2, acc[r][3] + bv3);
        *(float4*)&out[(size_t)grow * D + j0] = o4;
    }
}

extern "C" void kernel_launch(void* const* d_in, const int* in_sizes, int n_in,
                              void* d_out, int out_size, void* d_ws, size_t ws_size,
                              hipStream_t stream) {
    const float* x      = (const float*)d_in[0];
    const float* freqs  = (const float*)d_in[1];
    const int*   pos    = (const int*)d_in[2];
    const float* Wqkv   = (const float*)d_in[3];
    const float* bqkv   = (const float*)d_in[4];
    const float* Wdense = (const float*)d_in[5];
    const float* bdense = (const float*)d_in[6];
    float* out = (float*)d_out;

    const size_t nSD = (size_t)S * D;   // 4 Mi elems
    const size_t nW1 = (size_t)D * N3;  // 12 Mi elems
    const size_t nOP = (size_t)1024 * 64 * 128;   // split-K partial O (f32)
    const size_t nML = (size_t)1024 * 128;        // split-K partial m,l (f32)

    const size_t needed =
        (6 * nSD + nW1) * sizeof(ushort_t) + (nOP + nML) * sizeof(float);

    if (ws_size >= needed) {
        ushort_t* qh   = (ushort_t*)d_ws;
        ushort_t* kh   = qh + nSD;
        ushort_t* vh   = kh + nSD;
        ushort_t* ctxh = vh + nSD;
        ushort_t* xh   = ctxh + nSD;
        ushort_t* Wth  = xh + nSD;
        ushort_t* Wdth = Wth + nW1;
        float* Opart = (float*)(Wdth + nSD);
        float* MLpart = Opart + nOP;

        convert_f16_kernel<<<nSD / 4 / 512, 256, 0, stream>>>(x, xh);
        dim3 gt1(D / 32, N3 / 32);
        convert_t_kernel<<<gt1, 256, 0, stream>>>(Wqkv, Wth, D, N3);
        dim3 gt2(D / 32, D / 32);
        convert_t_kernel<<<gt2, 256, 0, stream>>>(Wdense, Wdth, D, D);

        dim3 g1(N3 / 128, S / 128);   // 48 x 16 = 768 blocks, 512 thr
        gemm_qkv_mfma<<<g1, 512, 0, stream>>>(xh, Wth, bqkv, freqs,
                                              pos, qh, kh, vh);
        attn_mfma_kernel<<<1024, 256, 0, stream>>>(qh, kh, vh,
                                                   Opart, MLpart);
        dim3 gc(32, H);
        attn_combine_kernel<<<gc, 128, 0, stream>>>(Opart, MLpart, ctxh);
        dim3 g3(D / 128, S / 64);     // 16 x 32 = 512 blocks, 512 thr
        gemm_dense_mfma<<<g3, 512, 0, stream>>>(ctxh, Wdth, bdense, out);
    } else {
        // fallback: R2 f32 path (needs only 64 MiB)
        float* qb  = (float*)d_ws;
        float* kb  = qb + (size_t)H * S * HD;
        float* vb  = kb + (size_t)H * S * HD;
        float* ctx = vb + (size_t)H * S * HD;
        dim3 g1(N3 / 64, S / 64);
        gemm_qkv_kernel<<<g1, 256, 0, stream>>>(x, Wqkv, bqkv, freqs, pos, qb, kb, vb);
        dim3 g2(16, H);
        attn_kernel<<<g2, 256, 0, stream>>>(qb, kb, vb, ctx);
        dim3 g3(D / 64, S / 64);
        gemm_dense_kernel<<<g3, 256, 0, stream>>>(ctx, Wdense, bdense, out);
    }
}

// Round 8
// 315.460 us; speedup vs baseline: 1.0620x; 1.0620x over previous
//
#include <hip/hip_runtime.h>

#define S 2048
#define D 2048
#define H 16
#define HD 128
#define N3 6144  // 3*D

typedef __attribute__((ext_vector_type(8))) _Float16 f16x8;
typedef __attribute__((ext_vector_type(4))) float f32x4;
typedef unsigned short ushort_t;
typedef unsigned int uint_t;

// ---------------------------------------------------------------------------
// f16 helpers (v_cvt_f16_f32 is RNE)
// ---------------------------------------------------------------------------
__device__ __forceinline__ ushort_t f16_rne(float f) {
    _Float16 h = (_Float16)f;
    return __builtin_bit_cast(ushort_t, h);
}
__device__ __forceinline__ float f16_f32(ushort_t u) {
    return (float)__builtin_bit_cast(_Float16, u);
}

// f32 row-major -> f16 (activations). 32B/thread (G13 vectorize).
__global__ __launch_bounds__(256) void convert_f16_kernel(
    const float* __restrict__ in, ushort_t* __restrict__ hi)
{
    const int base = blockIdx.x * 512 + threadIdx.x;   // per float4, x2
    const float4* in4 = (const float4*)in;
    float4 a = in4[base];
    float4 b = in4[base + 256];
    ((ushort4*)hi)[base] = make_ushort4(f16_rne(a.x), f16_rne(a.y),
                                        f16_rne(a.z), f16_rne(a.w));
    ((ushort4*)hi)[base + 256] = make_ushort4(f16_rne(b.x), f16_rne(b.y),
                                              f16_rne(b.z), f16_rne(b.w));
}

// W [K][N] f32 -> Wt [N][K] f16 (transpose + convert), 32x32 tiles.
// Load phase: ONE float4/thread (G13). LDS stores scalar (stride-33 keeps
// both phases conflict-free). Read phase unchanged (proven).
__global__ __launch_bounds__(256) void convert_t_kernel(
    const float* __restrict__ in, ushort_t* __restrict__ hi,
    int Kdim, int Ndim)
{
    __shared__ float tile[32][33];
    const int k0 = blockIdx.x * 32, n0 = blockIdx.y * 32;
    const int row = threadIdx.x >> 3;        // 0..31
    const int c4  = (threadIdx.x & 7) * 4;   // 0..28
    float4 v = *(const float4*)&in[(size_t)(k0 + row) * Ndim + n0 + c4];
    tile[row][c4 + 0] = v.x;
    tile[row][c4 + 1] = v.y;
    tile[row][c4 + 2] = v.z;
    tile[row][c4 + 3] = v.w;
    __syncthreads();
    const int n  = threadIdx.x >> 3;        // 0..31 local col
    const int kc = (threadIdx.x & 7) * 4;   // 0..28 local k chunk
    const float v0 = tile[kc + 0][n], v1 = tile[kc + 1][n];
    const float v2 = tile[kc + 2][n], v3 = tile[kc + 3][n];
    const size_t off = (size_t)(n0 + n) * Kdim + k0 + kc;
    *(ushort4*)&hi[off] = make_ushort4(f16_rne(v0), f16_rne(v1),
                                       f16_rne(v2), f16_rne(v3));
}

// ---------------------------------------------------------------------------
// async global->LDS, 16 B per lane, wave-uniform LDS base (HW adds lane*16).
// ---------------------------------------------------------------------------
__device__ __forceinline__ void gload16(const ushort_t* g, ushort_t* l) {
    __builtin_amdgcn_global_load_lds(
        (const __attribute__((address_space(1))) unsigned int*)g,
        (__attribute__((address_space(3))) unsigned int*)l, 16, 0, 0);
}

__device__ __forceinline__ void vwait4() { asm volatile("s_waitcnt vmcnt(4)" ::: "memory"); }
__device__ __forceinline__ void vwait3() { asm volatile("s_waitcnt vmcnt(3)" ::: "memory"); }
__device__ __forceinline__ void vwait0() { asm volatile("s_waitcnt vmcnt(0)" ::: "memory"); }
__device__ __forceinline__ void lwait0() { asm volatile("s_waitcnt lgkmcnt(0)" ::: "memory"); }

// ---------------------------------------------------------------------------
// R17 GEMM core (PROVEN R5/R6/R7: qkv ~84us, MfmaUtil 25.5%, 0 conflicts):
// 128x128 tile, 8 waves (512 thr), BK=64, dbuf 64 KB -> 2 blocks/CU =
// 16 waves/CU. TLP is the binding constraint (R5 A/B). Both-sides XOR
// swizzle; 2 barriers/tile; counted vmcnt(4). NO XCD swizzle (R4: L2 thrash).
// ---------------------------------------------------------------------------
#define QNT 32   // D / 64 K-tiles

__device__ __forceinline__ void mm_core_v4(
    const ushort_t* __restrict__ At, const ushort_t* __restrict__ Bt,
    ushort_t* lds, const int t, f32x4 (&acc)[4][2])
{
    const int w = t >> 6, lane = t & 63;
    const int lr = lane & 15, quad = lane >> 4;
    const int wm = (w >> 2) * 64;     // 2 m-groups
    const int wn = (w & 3) * 32;      // 4 n-groups

    const int srow = w * 8 + (lane >> 3);
    const int schk = ((lane & 7) ^ (lane >> 3)) * 8;
    const int ldsw = w * 512;   // wave-uniform

    auto stageAB = [&](int Tt) {
        ushort_t* dbase = lds + (Tt & 1) * 16384;
        const size_t koff = (size_t)Tt * 64 + schk;
        gload16(At + (size_t)srow * D + koff,        dbase + ldsw);
        gload16(At + (size_t)(srow + 64) * D + koff, dbase + 4096 + ldsw);
        gload16(Bt + (size_t)srow * D + koff,        dbase + 8192 + ldsw);
        gload16(Bt + (size_t)(srow + 64) * D + koff, dbase + 12288 + ldsw);
    };

    const int aoff = (wm + lr) * 64;
    const int boff = 8192 + (wn + lr) * 64;
    const int sw0 = ((0 * 4 + quad) ^ (lr & 7)) * 8;
    const int sw1 = ((1 * 4 + quad) ^ (lr & 7)) * 8;

    stageAB(0);
    stageAB(1);
    vwait4();                       // tile 0 landed (tile 1 in flight)
    __builtin_amdgcn_sched_barrier(0);
    __builtin_amdgcn_s_barrier();

    f16x8 a[4], b[2];
    for (int T = 0; T < QNT; T++) {
        const ushort_t* base = lds + (T & 1) * 16384;
        // ---- kk = 0 slice
        #pragma unroll
        for (int i = 0; i < 4; i++)
            a[i] = *(const f16x8*)&base[aoff + i * 1024 + sw0];
        #pragma unroll
        for (int n = 0; n < 2; n++)
            b[n] = *(const f16x8*)&base[boff + n * 1024 + sw0];
        lwait0();
        __builtin_amdgcn_sched_barrier(0);
        __builtin_amdgcn_s_setprio(1);
        #pragma unroll
        for (int i = 0; i < 4; i++)
            #pragma unroll
            for (int n = 0; n < 2; n++)
                acc[i][n] = __builtin_amdgcn_mfma_f32_16x16x32_f16(
                    a[i], b[n], acc[i][n], 0, 0, 0);
        __builtin_amdgcn_s_setprio(0);
        // ---- kk = 1 slice
        #pragma unroll
        for (int i = 0; i < 4; i++)
            a[i] = *(const f16x8*)&base[aoff + i * 1024 + sw1];
        #pragma unroll
        for (int n = 0; n < 2; n++)
            b[n] = *(const f16x8*)&base[boff + n * 1024 + sw1];
        lwait0();
        __builtin_amdgcn_sched_barrier(0);
        __builtin_amdgcn_s_barrier();   // all waves done reading buf T&1
        if (T < QNT - 2) stageAB(T + 2);
        __builtin_amdgcn_s_setprio(1);
        #pragma unroll
        for (int i = 0; i < 4; i++)
            #pragma unroll
            for (int n = 0; n < 2; n++)
                acc[i][n] = __builtin_amdgcn_mfma_f32_16x16x32_f16(
                    a[i], b[n], acc[i][n], 0, 0, 0);
        __builtin_amdgcn_s_setprio(0);
        if (T < QNT - 2)       vwait4();   // T+1 landed; T+2 in flight
        else if (T == QNT - 2) vwait0();   // drain last tile
        __builtin_amdgcn_s_barrier();
    }
}

// ---------------------------------------------------------------------------
// R18 dense core: 64x128 tile, 8 waves, BK=64, dbuf 48 KB, same schedule.
// ---------------------------------------------------------------------------
__device__ __forceinline__ void mm_core_v4h(
    const ushort_t* __restrict__ At, const ushort_t* __restrict__ Bt,
    ushort_t* lds, const int t, f32x4 (&acc)[2][2])
{
    const int w = t >> 6, lane = t & 63;
    const int lr = lane & 15, quad = lane >> 4;
    const int wm = (w >> 2) * 32;     // 2 m-groups over 64 rows
    const int wn = (w & 3) * 32;      // 4 n-groups over 128 cols

    const int srow = w * 8 + (lane >> 3);          // 0..63
    const int schk = ((lane & 7) ^ (lane >> 3)) * 8;
    const int ldsw = w * 512;

    auto stageAB = [&](int Tt) {
        ushort_t* dbase = lds + (Tt & 1) * 12288;
        const size_t koff = (size_t)Tt * 64 + schk;
        gload16(At + (size_t)srow * D + koff,        dbase + ldsw);          // A 0..63
        gload16(Bt + (size_t)srow * D + koff,        dbase + 4096 + ldsw);   // B 0..63
        gload16(Bt + (size_t)(srow + 64) * D + koff, dbase + 8192 + ldsw);   // B 64..127
    };

    const int aoff = (wm + lr) * 64;
    const int boff = 4096 + (wn + lr) * 64;
    const int sw0 = ((0 * 4 + quad) ^ (lr & 7)) * 8;
    const int sw1 = ((1 * 4 + quad) ^ (lr & 7)) * 8;

    stageAB(0);
    stageAB(1);
    vwait3();
    __builtin_amdgcn_sched_barrier(0);
    __builtin_amdgcn_s_barrier();

    f16x8 a[2], b[2];
    for (int T = 0; T < QNT; T++) {
        const ushort_t* base = lds + (T & 1) * 12288;
        // ---- kk = 0 slice
        #pragma unroll
        for (int i = 0; i < 2; i++)
            a[i] = *(const f16x8*)&base[aoff + i * 1024 + sw0];
        #pragma unroll
        for (int n = 0; n < 2; n++)
            b[n] = *(const f16x8*)&base[boff + n * 1024 + sw0];
        lwait0();
        __builtin_amdgcn_sched_barrier(0);
        __builtin_amdgcn_s_setprio(1);
        #pragma unroll
        for (int i = 0; i < 2; i++)
            #pragma unroll
            for (int n = 0; n < 2; n++)
                acc[i][n] = __builtin_amdgcn_mfma_f32_16x16x32_f16(
                    a[i], b[n], acc[i][n], 0, 0, 0);
        __builtin_amdgcn_s_setprio(0);
        // ---- kk = 1 slice
        #pragma unroll
        for (int i = 0; i < 2; i++)
            a[i] = *(const f16x8*)&base[aoff + i * 1024 + sw1];
        #pragma unroll
        for (int n = 0; n < 2; n++)
            b[n] = *(const f16x8*)&base[boff + n * 1024 + sw1];
        lwait0();
        __builtin_amdgcn_sched_barrier(0);
        __builtin_amdgcn_s_barrier();
        if (T < QNT - 2) stageAB(T + 2);
        __builtin_amdgcn_s_setprio(1);
        #pragma unroll
        for (int i = 0; i < 2; i++)
            #pragma unroll
            for (int n = 0; n < 2; n++)
                acc[i][n] = __builtin_amdgcn_mfma_f32_16x16x32_f16(
                    a[i], b[n], acc[i][n], 0, 0, 0);
        __builtin_amdgcn_s_setprio(0);
        if (T < QNT - 2)       vwait3();
        else if (T == QNT - 2) vwait0();
        __builtin_amdgcn_s_barrier();
    }
}

// ---------------------------------------------------------------------------
// QKV GEMM (f16 1-term, v4 core, 512 thr). q/k/v all stored f16.
// ---------------------------------------------------------------------------
__global__ __launch_bounds__(512, 4) void gemm_qkv_mfma(
    const ushort_t* __restrict__ xh,
    const ushort_t* __restrict__ Wth,
    const float* __restrict__ bias, const float* __restrict__ freqs,
    const int* __restrict__ input_pos,
    ushort_t* __restrict__ qhg, ushort_t* __restrict__ khg,
    ushort_t* __restrict__ vhg)
{
    __shared__ ushort_t lds[32768];   // 64 KB
    const int t = threadIdx.x;
    const int col0 = blockIdx.x * 128;
    const int row0 = blockIdx.y * 128;

    f32x4 acc[4][2] = {};
    mm_core_v4(xh + (size_t)row0 * D, Wth + (size_t)col0 * D, lds, t, acc);

    const int lane = t & 63;
    const int quad = lane >> 4;
    const int lr   = lane & 15;
    const int w = t >> 6;
    const int wm = (w >> 2) * 64;
    const int wn = (w & 3) * 32;

    const int which = col0 >> 11;           // 0=q 1=k 2=v (128 | 2048)
    const int hh = (col0 & 2047) >> 7;

    if (which == 2) {
        ushort_t* vh_b = vhg + (size_t)hh * HD * S;
        #pragma unroll
        for (int nt = 0; nt < 2; nt++) {
            const int d = wn + nt * 16 + lr;
            const float bsc = bias[col0 + d];
            #pragma unroll
            for (int mt = 0; mt < 4; mt++) {
                #pragma unroll
                for (int reg = 0; reg < 4; reg++) {
                    const int m = row0 + wm + mt * 16 + quad * 4 + reg;
                    const float v = acc[mt][nt][reg] + bsc;
                    vh_b[(size_t)d * S + input_pos[m]] = f16_rne(v);
                }
            }
        }
    } else {
        ushort_t* oh_b = ((which == 0) ? qhg : khg) + (size_t)hh * S * HD;
        #pragma unroll
        for (int nt = 0; nt < 2; nt++) {
            const int d = wn + nt * 16 + lr;
            const float bsc = bias[col0 + d];
            #pragma unroll
            for (int mt = 0; mt < 4; mt++) {
                #pragma unroll
                for (int reg = 0; reg < 4; reg++) {
                    const int m = row0 + wm + mt * 16 + quad * 4 + reg;
                    const float v = acc[mt][nt][reg] + bsc;
                    const float* fc = &freqs[((size_t)m * 64 + (d >> 1)) * 2];
                    const float cc = fc[0], ss = fc[1];
                    const float p = __shfl_xor(v, 1);
                    const float o = (d & 1) ? (v * cc + p * ss) : (v * cc - p * ss);
                    const ushort_t hv = f16_rne(o);
                    const int hp = __shfl_xor((int)hv, 1);
                    if (!(d & 1)) {
                        const int srowg = (which == 0) ? m : input_pos[m];
                        *(uint_t*)&oh_b[(size_t)srowg * HD + d] =
                            (uint_t)hv | ((uint_t)hp << 16);
                    }
                }
            }
        }
    }
}

// ---------------------------------------------------------------------------
// Dense GEMM (f16 1-term, v4h core, 512 thr, 64x128 tiles): out = ctx@Wd + b
// ---------------------------------------------------------------------------
__global__ __launch_bounds__(512, 4) void gemm_dense_mfma(
    const ushort_t* __restrict__ Ah,
    const ushort_t* __restrict__ Wth,
    const float* __restrict__ bias, float* __restrict__ out)
{
    __shared__ ushort_t lds[24576];   // 48 KB
    const int t = threadIdx.x;
    const int col0 = blockIdx.x * 128;
    const int row0 = blockIdx.y * 64;

    f32x4 acc[2][2] = {};
    mm_core_v4h(Ah + (size_t)row0 * D, Wth + (size_t)col0 * D, lds, t, acc);

    const int lane = t & 63;
    const int quad = lane >> 4;
    const int lr   = lane & 15;
    const int w = t >> 6;
    const int wm = (w >> 2) * 32;
    const int wn = (w & 3) * 32;

    #pragma unroll
    for (int nt = 0; nt < 2; nt++) {
        const int n = col0 + wn + nt * 16 + lr;
        const float bsc = bias[n];
        #pragma unroll
        for (int mt = 0; mt < 2; mt++) {
            #pragma unroll
            for (int reg = 0; reg < 4; reg++) {
                const int m = row0 + wm + mt * 16 + quad * 4 + reg;
                const float o = acc[mt][nt][reg] + bsc;
                const float po = __shfl_xor(o, 1);
                if (!(n & 1))
                    *(float2*)&out[(size_t)m * D + n] = make_float2(o, po);
            }
        }
    }
}

// ---------------------------------------------------------------------------
// MFMA flash attention, SPLIT-K x2 (KVBLK=32). R21: EXACT R6 version — R7's
// defer-max + setprio REVERTED (R7 A/B: −25us total; the tile loop is not
// VALU-bound, and setprio in 4-wave barrier-synced blocks at 4/CU is the
// m190 case where priority inversion starves co-resident blocks' staging).
// ---------------------------------------------------------------------------
__global__ __launch_bounds__(256, 4) void attn_mfma_kernel(
    const ushort_t* __restrict__ qhg, const ushort_t* __restrict__ khg,
    const ushort_t* __restrict__ vhg,
    float* __restrict__ Opart, float* __restrict__ MLpart)
{
    __shared__ ushort_t Khs[2][4096];   // [buf][hf*512.. key*32 + d8] per wave chunk
    __shared__ ushort_t Vhs[2][4096];   // [buf][dim*32 + key8]
    __shared__ ushort_t Ps[64 * 32];

    const int bi   = blockIdx.x;           // 0..1023
    const int h    = (bi & 7) + 8 * ((bi >> 3) & 1);
    const int half = (bi >> 4) & 1;
    const int qi   = bi >> 5;              // 0..31
    const int r = (h & 8) ? qi : (31 - qi);
    const int q0 = r * 64;
    const int nhalf = r + 1;
    const int kt0 = half * nhalf;
    const int kt1 = kt0 + nhalf;
    const int t = threadIdx.x;
    const int w = t >> 6, lane = t & 63;
    const int lr = lane & 15, quad = lane >> 4;

    const size_t qrow = (size_t)h * S + q0 + w * 16 + lr;
    f16x8 qf[4];
    #pragma unroll
    for (int ks = 0; ks < 4; ks++)
        qf[ks] = *(const f16x8*)&qhg[qrow * HD + ks * 32 + quad * 8];

    const ushort_t* kh_b = khg + (size_t)h * S * HD;
    const ushort_t* vh_b = vhg + (size_t)h * HD * S;

    const int keyq = lane >> 2;   // 0..15
    const int sub  = lane & 3;    // 16B chunk index

    auto stage = [&](int kt, int buf) {
        const int k0 = kt * 32;
        #pragma unroll
        for (int hf = 0; hf < 2; hf++) {
            const size_t ksrc = (size_t)(k0 + hf * 16 + keyq) * HD + w * 32 + sub * 8;
            gload16(kh_b + ksrc, &Khs[buf][w * 1024 + hf * 512]);
            const int dim = w * 32 + hf * 16 + keyq;
            const size_t vsrc = (size_t)dim * S + k0 + sub * 8;
            gload16(vh_b + vsrc, &Vhs[buf][(w * 32 + hf * 16) * 32]);
        }
    };

    f32x4 O[8] = {};
    f32x4 Ol = {0.f, 0.f, 0.f, 0.f};   // ones-column: per-row denom (unnorm)
    float mrow[4];
    #pragma unroll
    for (int rr = 0; rr < 4; rr++) mrow[rr] = -1e30f;

    f16x8 onesv;
    #pragma unroll
    for (int i = 0; i < 8; i++) onesv[i] = (_Float16)1.0f;

    const float kSc = 0.08838834764831845f * 1.4426950408889634f; // scale*log2e

    stage(kt0, 0);

    for (int kt = kt0; kt < kt1; kt++) {
        const int k0 = kt * 32;
        const int cur = (kt - kt0) & 1;
        __syncthreads();  // drains vmcnt -> tile kt visible; buf cur^1 free

        if (kt + 1 < kt1) stage(kt + 1, cur ^ 1);

        // ---- scores (f16 q*k, f32 accum)
        f32x4 sa[2];
        #pragma unroll
        for (int nt = 0; nt < 2; nt++) {
            f32x4 s = {0.f, 0.f, 0.f, 0.f};
            #pragma unroll
            for (int ks = 0; ks < 4; ks++) {
                f16x8 kf = *(const f16x8*)&Khs[cur][ks * 1024 + (nt * 16 + lr) * 32 + quad * 8];
                s = __builtin_amdgcn_mfma_f32_16x16x32_f16(qf[ks], kf, s, 0, 0, 0);
            }
            sa[nt] = s;
        }

        const int rowbase = q0 + w * 16 + quad * 4;
        const bool need_mask = (k0 + 31) > (q0 + w * 16);
        float alpha[4], pv0[4], pv1[4];
        #pragma unroll
        for (int rr = 0; rr < 4; rr++) {
            float z0 = sa[0][rr] * kSc;
            float z1 = sa[1][rr] * kSc;
            if (need_mask) {
                const int rowg = rowbase + rr;
                if (k0 + lr > rowg)      z0 = -1e30f;
                if (k0 + 16 + lr > rowg) z1 = -1e30f;
            }
            float rm = fmaxf(z0, z1);
            #pragma unroll
            for (int off = 1; off < 16; off <<= 1)
                rm = fmaxf(rm, __shfl_xor(rm, off));
            const float nm = fmaxf(mrow[rr], rm);
            alpha[rr] = exp2f(mrow[rr] - nm);
            pv0[rr] = exp2f(z0 - nm);
            pv1[rr] = exp2f(z1 - nm);
            mrow[rr] = nm;
        }

        #pragma unroll
        for (int rr = 0; rr < 4; rr++) {
            const int prow = (w * 16 + quad * 4 + rr) * 32;
            Ps[prow + lr]      = f16_rne(pv0[rr]);
            Ps[prow + 16 + lr] = f16_rne(pv1[rr]);
        }
        // no barrier: each wave reads only its own P rows (lgkmcnt orders)

        #pragma unroll
        for (int nt = 0; nt < 8; nt++)
            #pragma unroll
            for (int rr = 0; rr < 4; rr++)
                O[nt][rr] *= alpha[rr];
        #pragma unroll
        for (int rr = 0; rr < 4; rr++)
            Ol[rr] *= alpha[rr];
        const f16x8 pf = *(const f16x8*)&Ps[(w * 16 + lr) * 32 + quad * 8];
        #pragma unroll
        for (int nt = 0; nt < 8; nt++) {
            f16x8 vf = *(const f16x8*)&Vhs[cur][(nt * 16 + lr) * 32 + quad * 8];
            O[nt] = __builtin_amdgcn_mfma_f32_16x16x32_f16(pf, vf, O[nt], 0, 0, 0);
        }
        Ol = __builtin_amdgcn_mfma_f32_16x16x32_f16(pf, onesv, Ol, 0, 0, 0);
    }

    // ---- store unnormalized partial O + (m, l) for the combine pass
    float* Ob = Opart + (size_t)bi * 64 * 128;
    #pragma unroll
    for (int rr = 0; rr < 4; rr++) {
        const int row = w * 16 + quad * 4 + rr;
        #pragma unroll
        for (int nt = 0; nt < 8; nt++)
            Ob[(size_t)row * 128 + nt * 16 + lr] = O[nt][rr];
        if (lr == 0) {
            MLpart[(size_t)bi * 128 + row * 2 + 0] = mrow[rr];
            MLpart[(size_t)bi * 128 + row * 2 + 1] = Ol[rr];
        }
    }
}

// ---------------------------------------------------------------------------
// Exact online-softmax merge of the two split-K halves -> ctxh (f16).
// R21: vectorized (G13) — float4 loads (16B/lane) + ushort4 stores (8B/lane),
// 4 rows per step; was 4B/2B scalar over ~42 MB of traffic.
// ---------------------------------------------------------------------------
__global__ __launch_bounds__(128) void attn_combine_kernel(
    const float* __restrict__ Opart, const float* __restrict__ MLpart,
    ushort_t* __restrict__ ctxh)
{
    const int qt = blockIdx.x;   // 0..31 (qi in attn kernel)
    const int h  = blockIdx.y;   // 0..15
    const int t  = threadIdx.x;  // 0..127
    const int b0 = h | (qt << 5);          // half 0
    const int b1 = b0 | (1 << 4);          // half 1
    const int r = (h & 8) ? qt : (31 - qt);
    const int q0 = r * 64;

    __shared__ float sc[64][2];
    if (t < 64) {
        const float m0 = MLpart[(size_t)b0 * 128 + t * 2 + 0];
        const float l0 = MLpart[(size_t)b0 * 128 + t * 2 + 1];
        const float m1 = MLpart[(size_t)b1 * 128 + t * 2 + 0];
        const float l1 = MLpart[(size_t)b1 * 128 + t * 2 + 1];
        const float m = fmaxf(m0, m1);
        const float a0 = exp2f(m0 - m), a1 = exp2f(m1 - m);
        const float inv = 1.0f / (l0 * a0 + l1 * a1);
        sc[t][0] = a0 * inv;
        sc[t][1] = a1 * inv;
    }
    __syncthreads();

    const float* O0 = Opart + (size_t)b0 * 64 * 128;
    const float* O1 = Opart + (size_t)b1 * 64 * 128;
    const int rb = t >> 5;          // 0..3 (row within 4-row step)
    const int c4 = (t & 31) * 4;    // 0..124 (column, float4-aligned)
    for (int rs = 0; rs < 64; rs += 4) {
        const int row = rs + rb;
        float4 a = *(const float4*)&O0[(size_t)row * 128 + c4];
        float4 b = *(const float4*)&O1[(size_t)row * 128 + c4];
        const float s0 = sc[row][0], s1 = sc[row][1];
        ushort4 o = make_ushort4(f16_rne(a.x * s0 + b.x * s1),
                                 f16_rne(a.y * s0 + b.y * s1),
                                 f16_rne(a.z * s0 + b.z * s1),
                                 f16_rne(a.w * s0 + b.w * s1));
        *(ushort4*)&ctxh[(size_t)(q0 + row) * D + h * HD + c4] = o;
    }
}

// ---------------------------------------------------------------------------
// Fallback f32 path (R2, known-good) for small workspace.
// ---------------------------------------------------------------------------
__global__ __launch_bounds__(256) void gemm_qkv_kernel(
    const float* __restrict__ x, const float* __restrict__ W,
    const float* __restrict__ bias, const float* __restrict__ freqs,
    const int* __restrict__ input_pos,
    float* __restrict__ qb, float* __restrict__ kb, float* __restrict__ vb)
{
    __shared__ float As[16][68];
    __shared__ float Bs[16][64];
    const int bx = blockIdx.x;
    const int by = blockIdx.y;
    const int tid = threadIdx.x;
    const int tx = tid & 15, ty = tid >> 4;
    const int row0 = by * 64, col0 = bx * 64;
    const int am = tid >> 2;
    const int ak = (tid & 3) * 4;
    const int bk = tid >> 4;
    const int bn = (tid & 15) * 4;
    float acc[4][4] = {};
    for (int k0 = 0; k0 < D; k0 += 16) {
        float4 av = *(const float4*)&x[(size_t)(row0 + am) * D + k0 + ak];
        float4 bv = *(const float4*)&W[(size_t)(k0 + bk) * N3 + col0 + bn];
        __syncthreads();
        As[ak + 0][am] = av.x; As[ak + 1][am] = av.y;
        As[ak + 2][am] = av.z; As[ak + 3][am] = av.w;
        *(float4*)&Bs[bk][bn] = bv;
        __syncthreads();
        #pragma unroll
        for (int k = 0; k < 16; k++) {
            float4 a4 = *(const float4*)&As[k][ty * 4];
            float4 b4 = *(const float4*)&Bs[k][tx * 4];
            float a[4] = {a4.x, a4.y, a4.z, a4.w};
            float b[4] = {b4.x, b4.y, b4.z, b4.w};
            #pragma unroll
            for (int r = 0; r < 4; r++)
                #pragma unroll
                for (int c = 0; c < 4; c++)
                    acc[r][c] += a[r] * b[c];
        }
    }
    const int j0 = col0 + tx * 4;
    const int which = j0 >> 11;
    const int hh = (j0 & 2047) >> 7;
    const int d0 = j0 & 127;
    const float bv0 = bias[j0 + 0], bv1 = bias[j0 + 1];
    const float bv2 = bias[j0 + 2], bv3 = bias[j0 + 3];
    #pragma unroll
    for (int r = 0; r < 4; r++) {
        const int grow = row0 + ty * 4 + r;
        float v0 = acc[r][0] + bv0, v1 = acc[r][1] + bv1;
        float v2 = acc[r][2] + bv2, v3 = acc[r][3] + bv3;
        if (which == 2) {
            const int pos = input_pos[grow];
            float4 o4 = make_float4(v0, v1, v2, v3);
            *(float4*)&vb[((size_t)hh * S + pos) * HD + d0] = o4;
        } else {
            const float* fc = &freqs[((size_t)grow * 64 + (d0 >> 1)) * 2];
            float c0 = fc[0], s0 = fc[1], c1 = fc[2], s1 = fc[3];
            float o0 = v0 * c0 - v1 * s0, o1 = v1 * c0 + v0 * s0;
            float o2 = v2 * c1 - v3 * s1, o3 = v3 * c1 + v2 * s1;
            float4 o4 = make_float4(o0, o1, o2, o3);
            if (which == 0) {
                *(float4*)&qb[((size_t)hh * S + grow) * HD + d0] = o4;
            } else {
                const int pos = input_pos[grow];
                *(float4*)&kb[((size_t)hh * S + pos) * HD + d0] = o4;
            }
        }
    }
}

#define BQ 64
#define ABK 32
#define QSTR 132
#define KVSTR 132
#define PSTR 68

__global__ __launch_bounds__(256) void attn_kernel(
    const float* __restrict__ qb, const float* __restrict__ kb,
    const float* __restrict__ vb, float* __restrict__ ctx)
{
    __shared__ float Qs[BQ * QSTR];
    __shared__ float KV[ABK * KVSTR];
    __shared__ float Psf[ABK * PSTR];

    const int pa = blockIdx.x;
    const int h  = blockIdx.y;
    const int t  = threadIdx.x;
    const int ty = t >> 4, tx = t & 15;
    const int i0  = ty * 4;
    const int j0  = tx * 2;
    const int dd0 = tx * 8;
    const int lr = t >> 3;
    const int lc = (t & 7) * 4;

    const float* kbase = kb + (size_t)h * S * HD;
    const float* vbase = vb + (size_t)h * S * HD;
    const float kSc = 0.08838834764831845f * 1.4426950408889634f;

    for (int ph = 0; ph < 2; ph++) {
        const int r = (ph == 0) ? pa : 31 - pa;
        const int q0 = r * BQ;
        const int ntiles = 2 * r + 2;

        #pragma unroll
        for (int pp = 0; pp < 2; pp++) {
            const int iq = lr + pp * 32;
            const float* src = qb + ((size_t)h * S + q0 + iq) * HD;
            #pragma unroll
            for (int ch = 0; ch < 4; ch++)
                *(float4*)&Qs[iq * QSTR + lc + ch * 32] =
                    *(const float4*)&src[lc + ch * 32];
        }

        float O[4][8] = {};
        float m[4], l[4];
        #pragma unroll
        for (int rr = 0; rr < 4; rr++) { m[rr] = -1e30f; l[rr] = 0.f; }

        float4 kpref[4];
        #pragma unroll
        for (int ch = 0; ch < 4; ch++)
            kpref[ch] = *(const float4*)&kbase[(size_t)lr * HD + lc + ch * 32];

        __syncthreads();

        for (int kt = 0; kt < ntiles; kt++) {
            const int k0 = kt * ABK;

            #pragma unroll
            for (int ch = 0; ch < 4; ch++)
                *(float4*)&KV[lr * KVSTR + lc + ch * 32] = kpref[ch];
            __syncthreads();

            float4 vpref[4];
            #pragma unroll
            for (int ch = 0; ch < 4; ch++)
                vpref[ch] = *(const float4*)&vbase[(size_t)(k0 + lr) * HD + lc + ch * 32];

            float acc[4][2] = {};
            #pragma unroll 4
            for (int d0 = 0; d0 < HD; d0 += 4) {
                float4 ka = *(const float4*)&KV[(j0 + 0) * KVSTR + d0];
                float4 kb4 = *(const float4*)&KV[(j0 + 1) * KVSTR + d0];
                #pragma unroll
                for (int rr = 0; rr < 4; rr++) {
                    float4 q4 = *(const float4*)&Qs[(i0 + rr) * QSTR + d0];
                    acc[rr][0] += q4.x * ka.x + q4.y * ka.y + q4.z * ka.z + q4.w * ka.w;
                    acc[rr][1] += q4.x * kb4.x + q4.y * kb4.y + q4.z * kb4.z + q4.w * kb4.w;
                }
            }

            const bool need_mask = (k0 + ABK - 1) > q0;
            float p[4][2], alpha[4];
            #pragma unroll
            for (int rr = 0; rr < 4; rr++) {
                float z0 = acc[rr][0] * kSc;
                float z1 = acc[rr][1] * kSc;
                if (need_mask) {
                    if (k0 + j0 + 0 > q0 + i0 + rr) z0 = -1e30f;
                    if (k0 + j0 + 1 > q0 + i0 + rr) z1 = -1e30f;
                }
                float rmax = fmaxf(z0, z1);
                #pragma unroll
                for (int off = 1; off < 16; off <<= 1)
                    rmax = fmaxf(rmax, __shfl_xor(rmax, off, 16));
                const float nm = fmaxf(m[rr], rmax);
                alpha[rr] = exp2f(m[rr] - nm);
                p[rr][0] = exp2f(z0 - nm);
                p[rr][1] = exp2f(z1 - nm);
                float ts = p[rr][0] + p[rr][1];
                #pragma unroll
                for (int off = 1; off < 16; off <<= 1)
                    ts += __shfl_xor(ts, off, 16);
                l[rr] = l[rr] * alpha[rr] + ts;
                m[rr] = nm;
            }
            __syncthreads();

            #pragma unroll
            for (int ch = 0; ch < 4; ch++)
                *(float4*)&KV[lr * KVSTR + lc + ch * 32] = vpref[ch];
            *(float4*)&Psf[(j0 + 0) * PSTR + i0] =
                make_float4(p[0][0], p[1][0], p[2][0], p[3][0]);
            *(float4*)&Psf[(j0 + 1) * PSTR + i0] =
                make_float4(p[0][1], p[1][1], p[2][1], p[3][1]);
            if (kt + 1 < ntiles) {
                #pragma unroll
                for (int ch = 0; ch < 4; ch++)
                    kpref[ch] = *(const float4*)&kbase[(size_t)(k0 + ABK + lr) * HD + lc + ch * 32];
            }
            __syncthreads();

            #pragma unroll
            for (int rr = 0; rr < 4; rr++)
                #pragma unroll
                for (int c = 0; c < 8; c++)
                    O[rr][c] *= alpha[rr];
            #pragma unroll 4
            for (int j = 0; j < ABK; j++) {
                float4 pj = *(const float4*)&Psf[j * PSTR + i0];
                float4 v0 = *(const float4*)&KV[j * KVSTR + dd0];
                float4 v1 = *(const float4*)&KV[j * KVSTR + dd0 + 4];
                const float pr[4] = {pj.x, pj.y, pj.z, pj.w};
                const float vv[8] = {v0.x, v0.y, v0.z, v0.w, v1.x, v1.y, v1.z, v1.w};
                #pragma unroll
                for (int rr = 0; rr < 4; rr++)
                    #pragma unroll
                    for (int c = 0; c < 8; c++)
                        O[rr][c] += pr[rr] * vv[c];
            }
            __syncthreads();
        }

        #pragma unroll
        for (int rr = 0; rr < 4; rr++) {
            const float inv = 1.0f / l[rr];
            const int qg = q0 + i0 + rr;
            float4 o0 = make_float4(O[rr][0] * inv, O[rr][1] * inv,
                                    O[rr][2] * inv, O[rr][3] * inv);
            float4 o1 = make_float4(O[rr][4] * inv, O[rr][5] * inv,
                                    O[rr][6] * inv, O[rr][7] * inv);
            float* dst = &ctx[((size_t)qg * H + h) * HD + dd0];
            *(float4*)&dst[0] = o0;
            *(float4*)&dst[4] = o1;
        }
        __syncthreads();
    }
}

__global__ __launch_bounds__(256) void gemm_dense_kernel(
    const float* __restrict__ A, const float* __restrict__ W,
    const float* __restrict__ bias, float* __restrict__ out)
{
    __shared__ float As[16][68];
    __shared__ float Bs[16][64];
    const int bx = blockIdx.x;
    const int by = blockIdx.y;
    const int tid = threadIdx.x;
    const int tx = tid & 15, ty = tid >> 4;
    const int row0 = by * 64, col0 = bx * 64;
    const int am = tid >> 2;
    const int ak = (tid & 3) * 4;
    const int bk = tid >> 4;
    const int bn = (tid & 15) * 4;
    float acc[4][4] = {};
    for (int k0 = 0; k0 < D; k0 += 16) {
        float4 av = *(const float4*)&A[(size_t)(row0 + am) * D + k0 + ak];
        float4 bv = *(const float4*)&W[(size_t)(k0 + bk) * D + col0 + bn];
        __syncthreads();
        As[ak + 0][am] = av.x; As[ak + 1][am] = av.y;
        As[ak + 2][am] = av.z; As[ak + 3][am] = av.w;
        *(float4*)&Bs[bk][bn] = bv;
        __syncthreads();
        #pragma unroll
        for (int k = 0; k < 16; k++) {
            float4 a4 = *(const float4*)&As[k][ty * 4];
            float4 b4 = *(const float4*)&Bs[k][tx * 4];
            float a[4] = {a4.x, a4.y, a4.z, a4.w};
            float b[4] = {b4.x, b4.y, b4.z, b4.w};
            #pragma unroll
            for (int r = 0; r < 4; r++)
                #pragma unroll
                for (int c = 0; c < 4; c++)
                    acc[r][c] += a[r] * b[c];
        }
    }
    const int j0 = col0 + tx * 4;
    const float bv0 = bias[j0 + 0], bv1 = bias[j0 + 1];
    const float bv2 = bias[j0 + 2], bv3 = bias[j0 + 3];
    #pragma unroll
    for (int r = 0; r < 4; r++) {
        const int grow = row0 + ty * 4 + r;
        float4 o4 = make_float4(acc[r][0] + bv0, acc[r][1] + bv1,
                                acc[r][2] + bv2, acc[r][3] + bv3);
        *(float4*)&out[(size_t)grow * D + j0] = o4;
    }
}

extern "C" void kernel_launch(void* const* d_in, const int* in_sizes, int n_in,
                              void* d_out, int out_size, void* d_ws, size_t ws_size,
                              hipStream_t stream) {
    const float* x      = (const float*)d_in[0];
    const float* freqs  = (const float*)d_in[1];
    const int*   pos    = (const int*)d_in[2];
    const float* Wqkv   = (const float*)d_in[3];
    const float* bqkv   = (const float*)d_in[4];
    const float* Wdense = (const float*)d_in[5];
    const float* bdense = (const float*)d_in[6];
    float* out = (float*)d_out;

    const size_t nSD = (size_t)S * D;   // 4 Mi elems
    const size_t nW1 = (size_t)D * N3;  // 12 Mi elems
    const size_t nOP = (size_t)1024 * 64 * 128;   // split-K partial O (f32)
    const size_t nML = (size_t)1024 * 128;        // split-K partial m,l (f32)

    const size_t needed =
        (6 * nSD + nW1) * sizeof(ushort_t) + (nOP + nML) * sizeof(float);

    if (ws_size >= needed) {
        ushort_t* qh   = (ushort_t*)d_ws;
        ushort_t* kh   = qh + nSD;
        ushort_t* vh   = kh + nSD;
        ushort_t* ctxh = vh + nSD;
        ushort_t* xh   = ctxh + nSD;
        ushort_t* Wth  = xh + nSD;
        ushort_t* Wdth = Wth + nW1;
        float* Opart = (float*)(Wdth + nSD);
        float* MLpart = Opart + nOP;

        convert_f16_kernel<<<nSD / 4 / 512, 256, 0, stream>>>(x, xh);
        dim3 gt1(D / 32, N3 / 32);
        convert_t_kernel<<<gt1, 256, 0, stream>>>(Wqkv, Wth, D, N3);
        dim3 gt2(D / 32, D / 32);
        convert_t_kernel<<<gt2, 256, 0, stream>>>(Wdense, Wdth, D, D);

        dim3 g1(N3 / 128, S / 128);   // 48 x 16 = 768 blocks, 512 thr
        gemm_qkv_mfma<<<g1, 512, 0, stream>>>(xh, Wth, bqkv, freqs,
                                              pos, qh, kh, vh);
        attn_mfma_kernel<<<1024, 256, 0, stream>>>(qh, kh, vh,
                                                   Opart, MLpart);
        dim3 gc(32, H);
        attn_combine_kernel<<<gc, 128, 0, stream>>>(Opart, MLpart, ctxh);
        dim3 g3(D / 128, S / 64);     // 16 x 32 = 512 blocks, 512 thr
        gemm_dense_mfma<<<g3, 512, 0, stream>>>(ctxh, Wdth, bdense, out);
    } else {
        // fallback: R2 f32 path (needs only 64 MiB)
        float* qb  = (float*)d_ws;
        float* kb  = qb + (size_t)H * S * HD;
        float* vb  = kb + (size_t)H * S * HD;
        float* ctx = vb + (size_t)H * S * HD;
        dim3 g1(N3 / 64, S / 64);
        gemm_qkv_kernel<<<g1, 256, 0, stream>>>(x, Wqkv, bqkv, freqs, pos, qb, kb, vb);
        dim3 g2(16, H);
        attn_kernel<<<g2, 256, 0, stream>>>(qb, kb, vb, ctx);
        dim3 g3(D / 64, S / 64);
        gemm_dense_kernel<<<g3, 256, 0, stream>>>(ctx, Wdense, bdense, out);
    }
}

// Round 9
// 298.468 us; speedup vs baseline: 1.1224x; 1.0569x over previous
//
#include <hip/hip_runtime.h>

#define S 2048
#define D 2048
#define H 16
#define HD 128
#define N3 6144  // 3*D

typedef __attribute__((ext_vector_type(8))) _Float16 f16x8;
typedef __attribute__((ext_vector_type(4))) float f32x4;
typedef unsigned short ushort_t;
typedef unsigned int uint_t;

// ---------------------------------------------------------------------------
// f16 helpers (v_cvt_f16_f32 is RNE)
// ---------------------------------------------------------------------------
__device__ __forceinline__ ushort_t f16_rne(float f) {
    _Float16 h = (_Float16)f;
    return __builtin_bit_cast(ushort_t, h);
}
__device__ __forceinline__ float f16_f32(ushort_t u) {
    return (float)__builtin_bit_cast(_Float16, u);
}

// f32 row-major -> f16 (activations). 32B/thread (G13 vectorize).
__global__ __launch_bounds__(256) void convert_f16_kernel(
    const float* __restrict__ in, ushort_t* __restrict__ hi)
{
    const int base = blockIdx.x * 512 + threadIdx.x;   // per float4, x2
    const float4* in4 = (const float4*)in;
    float4 a = in4[base];
    float4 b = in4[base + 256];
    ((ushort4*)hi)[base] = make_ushort4(f16_rne(a.x), f16_rne(a.y),
                                        f16_rne(a.z), f16_rne(a.w));
    ((ushort4*)hi)[base + 256] = make_ushort4(f16_rne(b.x), f16_rne(b.y),
                                              f16_rne(b.z), f16_rne(b.w));
}

// W [K][N] f32 -> Wt [N][K] f16 (transpose + convert), 32x32 tiles.
// Load phase: ONE float4/thread (G13). Read phase unchanged (proven).
__global__ __launch_bounds__(256) void convert_t_kernel(
    const float* __restrict__ in, ushort_t* __restrict__ hi,
    int Kdim, int Ndim)
{
    __shared__ float tile[32][33];
    const int k0 = blockIdx.x * 32, n0 = blockIdx.y * 32;
    const int row = threadIdx.x >> 3;        // 0..31
    const int c4  = (threadIdx.x & 7) * 4;   // 0..28
    float4 v = *(const float4*)&in[(size_t)(k0 + row) * Ndim + n0 + c4];
    tile[row][c4 + 0] = v.x;
    tile[row][c4 + 1] = v.y;
    tile[row][c4 + 2] = v.z;
    tile[row][c4 + 3] = v.w;
    __syncthreads();
    const int n  = threadIdx.x >> 3;        // 0..31 local col
    const int kc = (threadIdx.x & 7) * 4;   // 0..28 local k chunk
    const float v0 = tile[kc + 0][n], v1 = tile[kc + 1][n];
    const float v2 = tile[kc + 2][n], v3 = tile[kc + 3][n];
    const size_t off = (size_t)(n0 + n) * Kdim + k0 + kc;
    *(ushort4*)&hi[off] = make_ushort4(f16_rne(v0), f16_rne(v1),
                                       f16_rne(v2), f16_rne(v3));
}

// ---------------------------------------------------------------------------
// async global->LDS, 16 B per lane, wave-uniform LDS base (HW adds lane*16).
// ---------------------------------------------------------------------------
__device__ __forceinline__ void gload16(const ushort_t* g, ushort_t* l) {
    __builtin_amdgcn_global_load_lds(
        (const __attribute__((address_space(1))) unsigned int*)g,
        (__attribute__((address_space(3))) unsigned int*)l, 16, 0, 0);
}

__device__ __forceinline__ void vwait5() { asm volatile("s_waitcnt vmcnt(5)" ::: "memory"); }
__device__ __forceinline__ void vwait3() { asm volatile("s_waitcnt vmcnt(3)" ::: "memory"); }
__device__ __forceinline__ void vwait0() { asm volatile("s_waitcnt vmcnt(0)" ::: "memory"); }
__device__ __forceinline__ void lwait0() { asm volatile("s_waitcnt lgkmcnt(0)" ::: "memory"); }

#define QNT 32   // D / 64 K-tiles

// ---------------------------------------------------------------------------
// R22 qkv core: 128x192 tile, 8 waves (512 thr), BK=64, dbuf 80 KB ->
// 2 blocks/CU (160 KB exact) = 16 waves/CU (the R5 TLP win, preserved).
// R8 post-mortem: at 4 waves/SIMD the per-barrier MFMA density (8/slice)
// is the next lever (R4's null on section length was measured at 2/SIMD).
// Wave tile 64x48 -> 12 MFMA/slice (+50% per-barrier work), acc[4][3].
// Same proven v4 schedule: 2 barriers/tile, counted vmcnt(5) (5 loads per
// stage: A x2 passes + B x3 passes; lead 2 tiles), both-sides XOR chunk
// swizzle (row&7 invariant under +64/+128 pass offsets). Grid 32x16 = 512
// blocks = exactly 2/CU, no tail wave. NO XCD swizzle (R4: L2 thrash).
// Failure signature if 160 KB exact fit fails: Occupancy ~15%, dur >110us.
// ---------------------------------------------------------------------------
#define BUFW 20480   // ushorts per buffer: A 8192 + B 12288

__device__ __forceinline__ void mm_core_v4w(
    const ushort_t* __restrict__ At, const ushort_t* __restrict__ Bt,
    ushort_t* lds, const int t, f32x4 (&acc)[4][3])
{
    const int w = t >> 6, lane = t & 63;
    const int lr = lane & 15, quad = lane >> 4;
    const int wm = (w >> 2) * 64;     // 2 m-groups over 128 rows
    const int wn = (w & 3) * 48;      // 4 n-groups over 192 cols

    const int srow = w * 8 + (lane >> 3);          // 0..63
    const int schk = ((lane & 7) ^ (lane >> 3)) * 8;
    const int ldsw = w * 512;   // wave-uniform

    auto stageAB = [&](int Tt) {
        ushort_t* dbase = lds + (Tt & 1) * BUFW;
        const size_t koff = (size_t)Tt * 64 + schk;
        gload16(At + (size_t)srow * D + koff,         dbase + ldsw);           // A 0..63
        gload16(At + (size_t)(srow + 64) * D + koff,  dbase + 4096 + ldsw);    // A 64..127
        gload16(Bt + (size_t)srow * D + koff,         dbase + 8192 + ldsw);    // B 0..63
        gload16(Bt + (size_t)(srow + 64) * D + koff,  dbase + 12288 + ldsw);   // B 64..127
        gload16(Bt + (size_t)(srow + 128) * D + koff, dbase + 16384 + ldsw);   // B 128..191
    };

    const int aoff = (wm + lr) * 64;
    const int boff = 8192 + (wn + lr) * 64;
    const int sw0 = ((0 * 4 + quad) ^ (lr & 7)) * 8;
    const int sw1 = ((1 * 4 + quad) ^ (lr & 7)) * 8;

    stageAB(0);
    stageAB(1);
    vwait5();                       // tile 0's 5 loads landed (tile 1 in flight)
    __builtin_amdgcn_sched_barrier(0);
    __builtin_amdgcn_s_barrier();

    f16x8 a[4], b[3];
    for (int T = 0; T < QNT; T++) {
        const ushort_t* base = lds + (T & 1) * BUFW;
        // ---- kk = 0 slice
        #pragma unroll
        for (int i = 0; i < 4; i++)
            a[i] = *(const f16x8*)&base[aoff + i * 1024 + sw0];
        #pragma unroll
        for (int n = 0; n < 3; n++)
            b[n] = *(const f16x8*)&base[boff + n * 1024 + sw0];
        lwait0();
        __builtin_amdgcn_sched_barrier(0);
        __builtin_amdgcn_s_setprio(1);
        #pragma unroll
        for (int i = 0; i < 4; i++)
            #pragma unroll
            for (int n = 0; n < 3; n++)
                acc[i][n] = __builtin_amdgcn_mfma_f32_16x16x32_f16(
                    a[i], b[n], acc[i][n], 0, 0, 0);
        __builtin_amdgcn_s_setprio(0);
        // ---- kk = 1 slice
        #pragma unroll
        for (int i = 0; i < 4; i++)
            a[i] = *(const f16x8*)&base[aoff + i * 1024 + sw1];
        #pragma unroll
        for (int n = 0; n < 3; n++)
            b[n] = *(const f16x8*)&base[boff + n * 1024 + sw1];
        lwait0();
        __builtin_amdgcn_sched_barrier(0);
        __builtin_amdgcn_s_barrier();   // all waves done reading buf T&1
        if (T < QNT - 2) stageAB(T + 2);
        __builtin_amdgcn_s_setprio(1);
        #pragma unroll
        for (int i = 0; i < 4; i++)
            #pragma unroll
            for (int n = 0; n < 3; n++)
                acc[i][n] = __builtin_amdgcn_mfma_f32_16x16x32_f16(
                    a[i], b[n], acc[i][n], 0, 0, 0);
        __builtin_amdgcn_s_setprio(0);
        if (T < QNT - 2)       vwait5();   // T+1's 5 landed; T+2's in flight
        else if (T == QNT - 2) vwait0();   // drain last tile
        __builtin_amdgcn_s_barrier();
    }
}

// ---------------------------------------------------------------------------
// R18 dense core: 64x128 tile, 8 waves, BK=64, dbuf 48 KB (proven R6).
// ---------------------------------------------------------------------------
__device__ __forceinline__ void mm_core_v4h(
    const ushort_t* __restrict__ At, const ushort_t* __restrict__ Bt,
    ushort_t* lds, const int t, f32x4 (&acc)[2][2])
{
    const int w = t >> 6, lane = t & 63;
    const int lr = lane & 15, quad = lane >> 4;
    const int wm = (w >> 2) * 32;     // 2 m-groups over 64 rows
    const int wn = (w & 3) * 32;      // 4 n-groups over 128 cols

    const int srow = w * 8 + (lane >> 3);          // 0..63
    const int schk = ((lane & 7) ^ (lane >> 3)) * 8;
    const int ldsw = w * 512;

    auto stageAB = [&](int Tt) {
        ushort_t* dbase = lds + (Tt & 1) * 12288;
        const size_t koff = (size_t)Tt * 64 + schk;
        gload16(At + (size_t)srow * D + koff,        dbase + ldsw);          // A 0..63
        gload16(Bt + (size_t)srow * D + koff,        dbase + 4096 + ldsw);   // B 0..63
        gload16(Bt + (size_t)(srow + 64) * D + koff, dbase + 8192 + ldsw);   // B 64..127
    };

    const int aoff = (wm + lr) * 64;
    const int boff = 4096 + (wn + lr) * 64;
    const int sw0 = ((0 * 4 + quad) ^ (lr & 7)) * 8;
    const int sw1 = ((1 * 4 + quad) ^ (lr & 7)) * 8;

    stageAB(0);
    stageAB(1);
    vwait3();
    __builtin_amdgcn_sched_barrier(0);
    __builtin_amdgcn_s_barrier();

    f16x8 a[2], b[2];
    for (int T = 0; T < QNT; T++) {
        const ushort_t* base = lds + (T & 1) * 12288;
        // ---- kk = 0 slice
        #pragma unroll
        for (int i = 0; i < 2; i++)
            a[i] = *(const f16x8*)&base[aoff + i * 1024 + sw0];
        #pragma unroll
        for (int n = 0; n < 2; n++)
            b[n] = *(const f16x8*)&base[boff + n * 1024 + sw0];
        lwait0();
        __builtin_amdgcn_sched_barrier(0);
        __builtin_amdgcn_s_setprio(1);
        #pragma unroll
        for (int i = 0; i < 2; i++)
            #pragma unroll
            for (int n = 0; n < 2; n++)
                acc[i][n] = __builtin_amdgcn_mfma_f32_16x16x32_f16(
                    a[i], b[n], acc[i][n], 0, 0, 0);
        __builtin_amdgcn_s_setprio(0);
        // ---- kk = 1 slice
        #pragma unroll
        for (int i = 0; i < 2; i++)
            a[i] = *(const f16x8*)&base[aoff + i * 1024 + sw1];
        #pragma unroll
        for (int n = 0; n < 2; n++)
            b[n] = *(const f16x8*)&base[boff + n * 1024 + sw1];
        lwait0();
        __builtin_amdgcn_sched_barrier(0);
        __builtin_amdgcn_s_barrier();
        if (T < QNT - 2) stageAB(T + 2);
        __builtin_amdgcn_s_setprio(1);
        #pragma unroll
        for (int i = 0; i < 2; i++)
            #pragma unroll
            for (int n = 0; n < 2; n++)
                acc[i][n] = __builtin_amdgcn_mfma_f32_16x16x32_f16(
                    a[i], b[n], acc[i][n], 0, 0, 0);
        __builtin_amdgcn_s_setprio(0);
        if (T < QNT - 2)       vwait3();
        else if (T == QNT - 2) vwait0();
        __builtin_amdgcn_s_barrier();
    }
}

// ---------------------------------------------------------------------------
// QKV GEMM (f16 1-term, v4w core, 512 thr, 128x192 tiles).
// 192 % 2048 boundary: `which` computed per nt (16-col groups; boundary is
// 16-aligned so which/hh are wave-uniform per nt).
// ---------------------------------------------------------------------------
__global__ __launch_bounds__(512, 4) void gemm_qkv_mfma(
    const ushort_t* __restrict__ xh,
    const ushort_t* __restrict__ Wth,
    const float* __restrict__ bias, const float* __restrict__ freqs,
    const int* __restrict__ input_pos,
    ushort_t* __restrict__ qhg, ushort_t* __restrict__ khg,
    ushort_t* __restrict__ vhg)
{
    __shared__ ushort_t lds[2 * BUFW];   // 80 KB
    const int t = threadIdx.x;
    const int col0 = blockIdx.x * 192;
    const int row0 = blockIdx.y * 128;

    f32x4 acc[4][3] = {};
    mm_core_v4w(xh + (size_t)row0 * D, Wth + (size_t)col0 * D, lds, t, acc);

    const int lane = t & 63;
    const int quad = lane >> 4;
    const int lr   = lane & 15;
    const int w = t >> 6;
    const int wm = (w >> 2) * 64;
    const int wn = (w & 3) * 48;

    #pragma unroll
    for (int nt = 0; nt < 3; nt++) {
        const int c = col0 + wn + nt * 16 + lr;
        const int which = c >> 11;          // wave-uniform per nt
        const int hh = (c & 2047) >> 7;
        const int d = c & 127;
        const float bsc = bias[c];
        if (which == 2) {
            ushort_t* vh_b = vhg + (size_t)hh * HD * S;
            #pragma unroll
            for (int mt = 0; mt < 4; mt++) {
                #pragma unroll
                for (int reg = 0; reg < 4; reg++) {
                    const int m = row0 + wm + mt * 16 + quad * 4 + reg;
                    const float v = acc[mt][nt][reg] + bsc;
                    vh_b[(size_t)d * S + input_pos[m]] = f16_rne(v);
                }
            }
        } else {
            ushort_t* oh_b = ((which == 0) ? qhg : khg) + (size_t)hh * S * HD;
            #pragma unroll
            for (int mt = 0; mt < 4; mt++) {
                #pragma unroll
                for (int reg = 0; reg < 4; reg++) {
                    const int m = row0 + wm + mt * 16 + quad * 4 + reg;
                    const float v = acc[mt][nt][reg] + bsc;
                    const float* fc = &freqs[((size_t)m * 64 + (d >> 1)) * 2];
                    const float cc = fc[0], ss = fc[1];
                    const float p = __shfl_xor(v, 1);
                    const float o = (d & 1) ? (v * cc + p * ss) : (v * cc - p * ss);
                    const ushort_t hv = f16_rne(o);
                    const int hp = __shfl_xor((int)hv, 1);
                    if (!(d & 1)) {
                        const int srowg = (which == 0) ? m : input_pos[m];
                        *(uint_t*)&oh_b[(size_t)srowg * HD + d] =
                            (uint_t)hv | ((uint_t)hp << 16);
                    }
                }
            }
        }
    }
}

// ---------------------------------------------------------------------------
// Dense GEMM (f16 1-term, v4h core, 512 thr, 64x128 tiles): out = ctx@Wd + b
// ---------------------------------------------------------------------------
__global__ __launch_bounds__(512, 4) void gemm_dense_mfma(
    const ushort_t* __restrict__ Ah,
    const ushort_t* __restrict__ Wth,
    const float* __restrict__ bias, float* __restrict__ out)
{
    __shared__ ushort_t lds[24576];   // 48 KB
    const int t = threadIdx.x;
    const int col0 = blockIdx.x * 128;
    const int row0 = blockIdx.y * 64;

    f32x4 acc[2][2] = {};
    mm_core_v4h(Ah + (size_t)row0 * D, Wth + (size_t)col0 * D, lds, t, acc);

    const int lane = t & 63;
    const int quad = lane >> 4;
    const int lr   = lane & 15;
    const int w = t >> 6;
    const int wm = (w >> 2) * 32;
    const int wn = (w & 3) * 32;

    #pragma unroll
    for (int nt = 0; nt < 2; nt++) {
        const int n = col0 + wn + nt * 16 + lr;
        const float bsc = bias[n];
        #pragma unroll
        for (int mt = 0; mt < 2; mt++) {
            #pragma unroll
            for (int reg = 0; reg < 4; reg++) {
                const int m = row0 + wm + mt * 16 + quad * 4 + reg;
                const float o = acc[mt][nt][reg] + bsc;
                const float po = __shfl_xor(o, 1);
                if (!(n & 1))
                    *(float2*)&out[(size_t)m * D + n] = make_float2(o, po);
            }
        }
    }
}

// ---------------------------------------------------------------------------
// MFMA flash attention, SPLIT-K x2 (KVBLK=32, R6 proven math/schedule).
// R22: partial O stored NORMALIZED f16 (O/l, guard l=0 -> 0): halves the
// split-K traffic (32->16 MB write+read). Combine folds l into the merge
// weights (w_i = a_i*l_i / sum) — exact same math.
// ---------------------------------------------------------------------------
__global__ __launch_bounds__(256, 4) void attn_mfma_kernel(
    const ushort_t* __restrict__ qhg, const ushort_t* __restrict__ khg,
    const ushort_t* __restrict__ vhg,
    ushort_t* __restrict__ Opart, float* __restrict__ MLpart)
{
    __shared__ ushort_t Khs[2][4096];   // [buf][hf*512.. key*32 + d8] per wave chunk
    __shared__ ushort_t Vhs[2][4096];   // [buf][dim*32 + key8]
    __shared__ ushort_t Ps[64 * 32];

    const int bi   = blockIdx.x;           // 0..1023
    const int h    = (bi & 7) + 8 * ((bi >> 3) & 1);
    const int half = (bi >> 4) & 1;
    const int qi   = bi >> 5;              // 0..31
    const int r = (h & 8) ? qi : (31 - qi);
    const int q0 = r * 64;
    const int nhalf = r + 1;
    const int kt0 = half * nhalf;
    const int kt1 = kt0 + nhalf;
    const int t = threadIdx.x;
    const int w = t >> 6, lane = t & 63;
    const int lr = lane & 15, quad = lane >> 4;

    const size_t qrow = (size_t)h * S + q0 + w * 16 + lr;
    f16x8 qf[4];
    #pragma unroll
    for (int ks = 0; ks < 4; ks++)
        qf[ks] = *(const f16x8*)&qhg[qrow * HD + ks * 32 + quad * 8];

    const ushort_t* kh_b = khg + (size_t)h * S * HD;
    const ushort_t* vh_b = vhg + (size_t)h * HD * S;

    const int keyq = lane >> 2;   // 0..15
    const int sub  = lane & 3;    // 16B chunk index

    auto stage = [&](int kt, int buf) {
        const int k0 = kt * 32;
        #pragma unroll
        for (int hf = 0; hf < 2; hf++) {
            const size_t ksrc = (size_t)(k0 + hf * 16 + keyq) * HD + w * 32 + sub * 8;
            gload16(kh_b + ksrc, &Khs[buf][w * 1024 + hf * 512]);
            const int dim = w * 32 + hf * 16 + keyq;
            const size_t vsrc = (size_t)dim * S + k0 + sub * 8;
            gload16(vh_b + vsrc, &Vhs[buf][(w * 32 + hf * 16) * 32]);
        }
    };

    f32x4 O[8] = {};
    f32x4 Ol = {0.f, 0.f, 0.f, 0.f};   // ones-column: per-row denom (unnorm)
    float mrow[4];
    #pragma unroll
    for (int rr = 0; rr < 4; rr++) mrow[rr] = -1e30f;

    f16x8 onesv;
    #pragma unroll
    for (int i = 0; i < 8; i++) onesv[i] = (_Float16)1.0f;

    const float kSc = 0.08838834764831845f * 1.4426950408889634f; // scale*log2e

    stage(kt0, 0);

    for (int kt = kt0; kt < kt1; kt++) {
        const int k0 = kt * 32;
        const int cur = (kt - kt0) & 1;
        __syncthreads();  // drains vmcnt -> tile kt visible; buf cur^1 free

        if (kt + 1 < kt1) stage(kt + 1, cur ^ 1);

        // ---- scores (f16 q*k, f32 accum)
        f32x4 sa[2];
        #pragma unroll
        for (int nt = 0; nt < 2; nt++) {
            f32x4 s = {0.f, 0.f, 0.f, 0.f};
            #pragma unroll
            for (int ks = 0; ks < 4; ks++) {
                f16x8 kf = *(const f16x8*)&Khs[cur][ks * 1024 + (nt * 16 + lr) * 32 + quad * 8];
                s = __builtin_amdgcn_mfma_f32_16x16x32_f16(qf[ks], kf, s, 0, 0, 0);
            }
            sa[nt] = s;
        }

        const int rowbase = q0 + w * 16 + quad * 4;
        const bool need_mask = (k0 + 31) > (q0 + w * 16);
        float alpha[4], pv0[4], pv1[4];
        #pragma unroll
        for (int rr = 0; rr < 4; rr++) {
            float z0 = sa[0][rr] * kSc;
            float z1 = sa[1][rr] * kSc;
            if (need_mask) {
                const int rowg = rowbase + rr;
                if (k0 + lr > rowg)      z0 = -1e30f;
                if (k0 + 16 + lr > rowg) z1 = -1e30f;
            }
            float rm = fmaxf(z0, z1);
            #pragma unroll
            for (int off = 1; off < 16; off <<= 1)
                rm = fmaxf(rm, __shfl_xor(rm, off));
            const float nm = fmaxf(mrow[rr], rm);
            alpha[rr] = exp2f(mrow[rr] - nm);
            pv0[rr] = exp2f(z0 - nm);
            pv1[rr] = exp2f(z1 - nm);
            mrow[rr] = nm;
        }

        #pragma unroll
        for (int rr = 0; rr < 4; rr++) {
            const int prow = (w * 16 + quad * 4 + rr) * 32;
            Ps[prow + lr]      = f16_rne(pv0[rr]);
            Ps[prow + 16 + lr] = f16_rne(pv1[rr]);
        }
        // no barrier: each wave reads only its own P rows (lgkmcnt orders)

        #pragma unroll
        for (int nt = 0; nt < 8; nt++)
            #pragma unroll
            for (int rr = 0; rr < 4; rr++)
                O[nt][rr] *= alpha[rr];
        #pragma unroll
        for (int rr = 0; rr < 4; rr++)
            Ol[rr] *= alpha[rr];
        const f16x8 pf = *(const f16x8*)&Ps[(w * 16 + lr) * 32 + quad * 8];
        #pragma unroll
        for (int nt = 0; nt < 8; nt++) {
            f16x8 vf = *(const f16x8*)&Vhs[cur][(nt * 16 + lr) * 32 + quad * 8];
            O[nt] = __builtin_amdgcn_mfma_f32_16x16x32_f16(pf, vf, O[nt], 0, 0, 0);
        }
        Ol = __builtin_amdgcn_mfma_f32_16x16x32_f16(pf, onesv, Ol, 0, 0, 0);
    }

    // ---- store NORMALIZED partial O (f16) + (m, l) for the combine pass
    ushort_t* Ob = Opart + (size_t)bi * 64 * 128;
    #pragma unroll
    for (int rr = 0; rr < 4; rr++) {
        const int row = w * 16 + quad * 4 + rr;
        const float inv = (Ol[rr] > 0.f) ? 1.0f / Ol[rr] : 0.f;
        #pragma unroll
        for (int nt = 0; nt < 8; nt++)
            Ob[(size_t)row * 128 + nt * 16 + lr] = f16_rne(O[nt][rr] * inv);
        if (lr == 0) {
            MLpart[(size_t)bi * 128 + row * 2 + 0] = mrow[rr];
            MLpart[(size_t)bi * 128 + row * 2 + 1] = Ol[rr];
        }
    }
}

// ---------------------------------------------------------------------------
// Exact online-softmax merge of the two split-K halves -> ctxh (f16).
// R22: parts are normalized f16; weights w_i = a_i*l_i / sum (exact merge).
// ushort4 loads (8B/lane) + ushort4 stores, 4 rows per step.
// ---------------------------------------------------------------------------
__global__ __launch_bounds__(128) void attn_combine_kernel(
    const ushort_t* __restrict__ Opart, const float* __restrict__ MLpart,
    ushort_t* __restrict__ ctxh)
{
    const int qt = blockIdx.x;   // 0..31 (qi in attn kernel)
    const int h  = blockIdx.y;   // 0..15
    const int t  = threadIdx.x;  // 0..127
    const int b0 = h | (qt << 5);          // half 0
    const int b1 = b0 | (1 << 4);          // half 1
    const int r = (h & 8) ? qt : (31 - qt);
    const int q0 = r * 64;

    __shared__ float sc[64][2];
    if (t < 64) {
        const float m0 = MLpart[(size_t)b0 * 128 + t * 2 + 0];
        const float l0 = MLpart[(size_t)b0 * 128 + t * 2 + 1];
        const float m1 = MLpart[(size_t)b1 * 128 + t * 2 + 0];
        const float l1 = MLpart[(size_t)b1 * 128 + t * 2 + 1];
        const float m = fmaxf(m0, m1);
        const float w0 = exp2f(m0 - m) * l0;
        const float w1 = exp2f(m1 - m) * l1;
        const float inv = 1.0f / (w0 + w1);   // w0 > 0 always (half0 has key 0)
        sc[t][0] = w0 * inv;
        sc[t][1] = w1 * inv;
    }
    __syncthreads();

    const ushort_t* O0 = Opart + (size_t)b0 * 64 * 128;
    const ushort_t* O1 = Opart + (size_t)b1 * 64 * 128;
    const int rb = t >> 5;          // 0..3 (row within 4-row step)
    const int c4 = (t & 31) * 4;    // 0..124 (column, ushort4-aligned)
    for (int rs = 0; rs < 64; rs += 4) {
        const int row = rs + rb;
        ushort4 ua = *(const ushort4*)&O0[(size_t)row * 128 + c4];
        ushort4 ub = *(const ushort4*)&O1[(size_t)row * 128 + c4];
        const float s0 = sc[row][0], s1 = sc[row][1];
        ushort4 o = make_ushort4(
            f16_rne(f16_f32(ua.x) * s0 + f16_f32(ub.x) * s1),
            f16_rne(f16_f32(ua.y) * s0 + f16_f32(ub.y) * s1),
            f16_rne(f16_f32(ua.z) * s0 + f16_f32(ub.z) * s1),
            f16_rne(f16_f32(ua.w) * s0 + f16_f32(ub.w) * s1));
        *(ushort4*)&ctxh[(size_t)(q0 + row) * D + h * HD + c4] = o;
    }
}

// ---------------------------------------------------------------------------
// Fallback f32 path (R2, known-good) for small workspace.
// ---------------------------------------------------------------------------
__global__ __launch_bounds__(256) void gemm_qkv_kernel(
    const float* __restrict__ x, const float* __restrict__ W,
    const float* __restrict__ bias, const float* __restrict__ freqs,
    const int* __restrict__ input_pos,
    float* __restrict__ qb, float* __restrict__ kb, float* __restrict__ vb)
{
    __shared__ float As[16][68];
    __shared__ float Bs[16][64];
    const int bx = blockIdx.x;
    const int by = blockIdx.y;
    const int tid = threadIdx.x;
    const int tx = tid & 15, ty = tid >> 4;
    const int row0 = by * 64, col0 = bx * 64;
    const int am = tid >> 2;
    const int ak = (tid & 3) * 4;
    const int bk = tid >> 4;
    const int bn = (tid & 15) * 4;
    float acc[4][4] = {};
    for (int k0 = 0; k0 < D; k0 += 16) {
        float4 av = *(const float4*)&x[(size_t)(row0 + am) * D + k0 + ak];
        float4 bv = *(const float4*)&W[(size_t)(k0 + bk) * N3 + col0 + bn];
        __syncthreads();
        As[ak + 0][am] = av.x; As[ak + 1][am] = av.y;
        As[ak + 2][am] = av.z; As[ak + 3][am] = av.w;
        *(float4*)&Bs[bk][bn] = bv;
        __syncthreads();
        #pragma unroll
        for (int k = 0; k < 16; k++) {
            float4 a4 = *(const float4*)&As[k][ty * 4];
            float4 b4 = *(const float4*)&Bs[k][tx * 4];
            float a[4] = {a4.x, a4.y, a4.z, a4.w};
            float b[4] = {b4.x, b4.y, b4.z, b4.w};
            #pragma unroll
            for (int r = 0; r < 4; r++)
                #pragma unroll
                for (int c = 0; c < 4; c++)
                    acc[r][c] += a[r] * b[c];
        }
    }
    const int j0 = col0 + tx * 4;
    const int which = j0 >> 11;
    const int hh = (j0 & 2047) >> 7;
    const int d0 = j0 & 127;
    const float bv0 = bias[j0 + 0], bv1 = bias[j0 + 1];
    const float bv2 = bias[j0 + 2], bv3 = bias[j0 + 3];
    #pragma unroll
    for (int r = 0; r < 4; r++) {
        const int grow = row0 + ty * 4 + r;
        float v0 = acc[r][0] + bv0, v1 = acc[r][1] + bv1;
        float v2 = acc[r][2] + bv2, v3 = acc[r][3] + bv3;
        if (which == 2) {
            const int pos = input_pos[grow];
            float4 o4 = make_float4(v0, v1, v2, v3);
            *(float4*)&vb[((size_t)hh * S + pos) * HD + d0] = o4;
        } else {
            const float* fc = &freqs[((size_t)grow * 64 + (d0 >> 1)) * 2];
            float c0 = fc[0], s0 = fc[1], c1 = fc[2], s1 = fc[3];
            float o0 = v0 * c0 - v1 * s0, o1 = v1 * c0 + v0 * s0;
            float o2 = v2 * c1 - v3 * s1, o3 = v3 * c1 + v2 * s1;
            float4 o4 = make_float4(o0, o1, o2, o3);
            if (which == 0) {
                *(float4*)&qb[((size_t)hh * S + grow) * HD + d0] = o4;
            } else {
                const int pos = input_pos[grow];
                *(float4*)&kb[((size_t)hh * S + pos) * HD + d0] = o4;
            }
        }
    }
}

#define BQ 64
#define ABK 32
#define QSTR 132
#define KVSTR 132
#define PSTR 68

__global__ __launch_bounds__(256) void attn_kernel(
    const float* __restrict__ qb, const float* __restrict__ kb,
    const float* __restrict__ vb, float* __restrict__ ctx)
{
    __shared__ float Qs[BQ * QSTR];
    __shared__ float KV[ABK * KVSTR];
    __shared__ float Psf[ABK * PSTR];

    const int pa = blockIdx.x;
    const int h  = blockIdx.y;
    const int t  = threadIdx.x;
    const int ty = t >> 4, tx = t & 15;
    const int i0  = ty * 4;
    const int j0  = tx * 2;
    const int dd0 = tx * 8;
    const int lr = t >> 3;
    const int lc = (t & 7) * 4;

    const float* kbase = kb + (size_t)h * S * HD;
    const float* vbase = vb + (size_t)h * S * HD;
    const float kSc = 0.08838834764831845f * 1.4426950408889634f;

    for (int ph = 0; ph < 2; ph++) {
        const int r = (ph == 0) ? pa : 31 - pa;
        const int q0 = r * BQ;
        const int ntiles = 2 * r + 2;

        #pragma unroll
        for (int pp = 0; pp < 2; pp++) {
            const int iq = lr + pp * 32;
            const float* src = qb + ((size_t)h * S + q0 + iq) * HD;
            #pragma unroll
            for (int ch = 0; ch < 4; ch++)
                *(float4*)&Qs[iq * QSTR + lc + ch * 32] =
                    *(const float4*)&src[lc + ch * 32];
        }

        float O[4][8] = {};
        float m[4], l[4];
        #pragma unroll
        for (int rr = 0; rr < 4; rr++) { m[rr] = -1e30f; l[rr] = 0.f; }

        float4 kpref[4];
        #pragma unroll
        for (int ch = 0; ch < 4; ch++)
            kpref[ch] = *(const float4*)&kbase[(size_t)lr * HD + lc + ch * 32];

        __syncthreads();

        for (int kt = 0; kt < ntiles; kt++) {
            const int k0 = kt * ABK;

            #pragma unroll
            for (int ch = 0; ch < 4; ch++)
                *(float4*)&KV[lr * KVSTR + lc + ch * 32] = kpref[ch];
            __syncthreads();

            float4 vpref[4];
            #pragma unroll
            for (int ch = 0; ch < 4; ch++)
                vpref[ch] = *(const float4*)&vbase[(size_t)(k0 + lr) * HD + lc + ch * 32];

            float acc[4][2] = {};
            #pragma unroll 4
            for (int d0 = 0; d0 < HD; d0 += 4) {
                float4 ka = *(const float4*)&KV[(j0 + 0) * KVSTR + d0];
                float4 kb4 = *(const float4*)&KV[(j0 + 1) * KVSTR + d0];
                #pragma unroll
                for (int rr = 0; rr < 4; rr++) {
                    float4 q4 = *(const float4*)&Qs[(i0 + rr) * QSTR + d0];
                    acc[rr][0] += q4.x * ka.x + q4.y * ka.y + q4.z * ka.z + q4.w * ka.w;
                    acc[rr][1] += q4.x * kb4.x + q4.y * kb4.y + q4.z * kb4.z + q4.w * kb4.w;
                }
            }

            const bool need_mask = (k0 + ABK - 1) > q0;
            float p[4][2], alpha[4];
            #pragma unroll
            for (int rr = 0; rr < 4; rr++) {
                float z0 = acc[rr][0] * kSc;
                float z1 = acc[rr][1] * kSc;
                if (need_mask) {
                    if (k0 + j0 + 0 > q0 + i0 + rr) z0 = -1e30f;
                    if (k0 + j0 + 1 > q0 + i0 + rr) z1 = -1e30f;
                }
                float rmax = fmaxf(z0, z1);
                #pragma unroll
                for (int off = 1; off < 16; off <<= 1)
                    rmax = fmaxf(rmax, __shfl_xor(rmax, off, 16));
                const float nm = fmaxf(m[rr], rmax);
                alpha[rr] = exp2f(m[rr] - nm);
                p[rr][0] = exp2f(z0 - nm);
                p[rr][1] = exp2f(z1 - nm);
                float ts = p[rr][0] + p[rr][1];
                #pragma unroll
                for (int off = 1; off < 16; off <<= 1)
                    ts += __shfl_xor(ts, off, 16);
                l[rr] = l[rr] * alpha[rr] + ts;
                m[rr] = nm;
            }
            __syncthreads();

            #pragma unroll
            for (int ch = 0; ch < 4; ch++)
                *(float4*)&KV[lr * KVSTR + lc + ch * 32] = vpref[ch];
            *(float4*)&Psf[(j0 + 0) * PSTR + i0] =
                make_float4(p[0][0], p[1][0], p[2][0], p[3][0]);
            *(float4*)&Psf[(j0 + 1) * PSTR + i0] =
                make_float4(p[0][1], p[1][1], p[2][1], p[3][1]);
            if (kt + 1 < ntiles) {
                #pragma unroll
                for (int ch = 0; ch < 4; ch++)
                    kpref[ch] = *(const float4*)&kbase[(size_t)(k0 + ABK + lr) * HD + lc + ch * 32];
            }
            __syncthreads();

            #pragma unroll
            for (int rr = 0; rr < 4; rr++)
                #pragma unroll
                for (int c = 0; c < 8; c++)
                    O[rr][c] *= alpha[rr];
            #pragma unroll 4
            for (int j = 0; j < ABK; j++) {
                float4 pj = *(const float4*)&Psf[j * PSTR + i0];
                float4 v0 = *(const float4*)&KV[j * KVSTR + dd0];
                float4 v1 = *(const float4*)&KV[j * KVSTR + dd0 + 4];
                const float pr[4] = {pj.x, pj.y, pj.z, pj.w};
                const float vv[8] = {v0.x, v0.y, v0.z, v0.w, v1.x, v1.y, v1.z, v1.w};
                #pragma unroll
                for (int rr = 0; rr < 4; rr++)
                    #pragma unroll
                    for (int c = 0; c < 8; c++)
                        O[rr][c] += pr[rr] * vv[c];
            }
            __syncthreads();
        }

        #pragma unroll
        for (int rr = 0; rr < 4; rr++) {
            const float inv = 1.0f / l[rr];
            const int qg = q0 + i0 + rr;
            float4 o0 = make_float4(O[rr][0] * inv, O[rr][1] * inv,
                                    O[rr][2] * inv, O[rr][3] * inv);
            float4 o1 = make_float4(O[rr][4] * inv, O[rr][5] * inv,
                                    O[rr][6] * inv, O[rr][7] * inv);
            float* dst = &ctx[((size_t)qg * H + h) * HD + dd0];
            *(float4*)&dst[0] = o0;
            *(float4*)&dst[4] = o1;
        }
        __syncthreads();
    }
}

__global__ __launch_bounds__(256) void gemm_dense_kernel(
    const float* __restrict__ A, const float* __restrict__ W,
    const float* __restrict__ bias, float* __restrict__ out)
{
    __shared__ float As[16][68];
    __shared__ float Bs[16][64];
    const int bx = blockIdx.x;
    const int by = blockIdx.y;
    const int tid = threadIdx.x;
    const int tx = tid & 15, ty = tid >> 4;
    const int row0 = by * 64, col0 = bx * 64;
    const int am = tid >> 2;
    const int ak = (tid & 3) * 4;
    const int bk = tid >> 4;
    const int bn = (tid & 15) * 4;
    float acc[4][4] = {};
    for (int k0 = 0; k0 < D; k0 += 16) {
        float4 av = *(const float4*)&A[(size_t)(row0 + am) * D + k0 + ak];
        float4 bv = *(const float4*)&W[(size_t)(k0 + bk) * D + col0 + bn];
        __syncthreads();
        As[ak + 0][am] = av.x; As[ak + 1][am] = av.y;
        As[ak + 2][am] = av.z; As[ak + 3][am] = av.w;
        *(float4*)&Bs[bk][bn] = bv;
        __syncthreads();
        #pragma unroll
        for (int k = 0; k < 16; k++) {
            float4 a4 = *(const float4*)&As[k][ty * 4];
            float4 b4 = *(const float4*)&Bs[k][tx * 4];
            float a[4] = {a4.x, a4.y, a4.z, a4.w};
            float b[4] = {b4.x, b4.y, b4.z, b4.w};
            #pragma unroll
            for (int r = 0; r < 4; r++)
                #pragma unroll
                for (int c = 0; c < 4; c++)
                    acc[r][c] += a[r] * b[c];
        }
    }
    const int j0 = col0 + tx * 4;
    const float bv0 = bias[j0 + 0], bv1 = bias[j0 + 1];
    const float bv2 = bias[j0 + 2], bv3 = bias[j0 + 3];
    #pragma unroll
    for (int r = 0; r < 4; r++) {
        const int grow = row0 + ty * 4 + r;
        float4 o4 = make_float4(acc[r][0] + bv0, acc[r][1] + bv1,
                                acc[r][2] + bv2, acc[r][3] + bv3);
        *(float4*)&out[(size_t)grow * D + j0] = o4;
    }
}

extern "C" void kernel_launch(void* const* d_in, const int* in_sizes, int n_in,
                              void* d_out, int out_size, void* d_ws, size_t ws_size,
                              hipStream_t stream) {
    const float* x      = (const float*)d_in[0];
    const float* freqs  = (const float*)d_in[1];
    const int*   pos    = (const int*)d_in[2];
    const float* Wqkv   = (const float*)d_in[3];
    const float* bqkv   = (const float*)d_in[4];
    const float* Wdense = (const float*)d_in[5];
    const float* bdense = (const float*)d_in[6];
    float* out = (float*)d_out;

    const size_t nSD = (size_t)S * D;   // 4 Mi elems
    const size_t nW1 = (size_t)D * N3;  // 12 Mi elems
    const size_t nOP = (size_t)1024 * 64 * 128;   // split-K partial O (f16 now)
    const size_t nML = (size_t)1024 * 128;        // split-K partial m,l (f32)

    const size_t needed =
        (6 * nSD + nW1 + nOP) * sizeof(ushort_t) + nML * sizeof(float);

    if (ws_size >= needed) {
        ushort_t* qh   = (ushort_t*)d_ws;
        ushort_t* kh   = qh + nSD;
        ushort_t* vh   = kh + nSD;
        ushort_t* ctxh = vh + nSD;
        ushort_t* xh   = ctxh + nSD;
        ushort_t* Wth  = xh + nSD;
        ushort_t* Wdth = Wth + nW1;
        ushort_t* Opart = Wdth + nSD;
        float* MLpart = (float*)(Opart + nOP);

        convert_f16_kernel<<<nSD / 4 / 512, 256, 0, stream>>>(x, xh);
        dim3 gt1(D / 32, N3 / 32);
        convert_t_kernel<<<gt1, 256, 0, stream>>>(Wqkv, Wth, D, N3);
        dim3 gt2(D / 32, D / 32);
        convert_t_kernel<<<gt2, 256, 0, stream>>>(Wdense, Wdth, D, D);

        dim3 g1(N3 / 192, S / 128);   // 32 x 16 = 512 blocks, 512 thr
        gemm_qkv_mfma<<<g1, 512, 0, stream>>>(xh, Wth, bqkv, freqs,
                                              pos, qh, kh, vh);
        attn_mfma_kernel<<<1024, 256, 0, stream>>>(qh, kh, vh,
                                                   Opart, MLpart);
        dim3 gc(32, H);
        attn_combine_kernel<<<gc, 128, 0, stream>>>(Opart, MLpart, ctxh);
        dim3 g3(D / 128, S / 64);     // 16 x 32 = 512 blocks, 512 thr
        gemm_dense_mfma<<<g3, 512, 0, stream>>>(ctxh, Wdth, bdense, out);
    } else {
        // fallback: R2 f32 path (needs only 64 MiB)
        float* qb  = (float*)d_ws;
        float* kb  = qb + (size_t)H * S * HD;
        float* vb  = kb + (size_t)H * S * HD;
        float* ctx = vb + (size_t)H * S * HD;
        dim3 g1(N3 / 64, S / 64);
        gemm_qkv_kernel<<<g1, 256, 0, stream>>>(x, Wqkv, bqkv, freqs, pos, qb, kb, vb);
        dim3 g2(16, H);
        attn_kernel<<<g2, 256, 0, stream>>>(qb, kb, vb, ctx);
        dim3 g3(D / 64, S / 64);
        gemm_dense_kernel<<<g3, 256, 0, stream>>>(ctx, Wdense, bdense, out);
    }
}